// Round 2
// baseline (167.876 us; speedup 1.0000x reference)
//
#include <hip/hip_runtime.h>
#include <stdint.h>

#define BB 64
#define SS 512
#define DPP 12   // padded head dim (48B rows -> float4 aligned)
#define EPSF 1e-5f

typedef float v2f __attribute__((ext_vector_type(2)));

// ---------------- K1: LN1 + QKV projection ----------------
// grid 512 x 256. Block = 64 rows; wave = j-part (32 cols), lane = row.
__global__ __launch_bounds__(256) void k_ln_qkv(
    const float* __restrict__ x, const float* __restrict__ g, const float* __restrict__ be,
    const float* __restrict__ Wq, const float* __restrict__ bq,
    const float* __restrict__ Wk, const float* __restrict__ bk,
    const float* __restrict__ Wv, const float* __restrict__ bv,
    float* __restrict__ qo, float* __restrict__ ko, float* __restrict__ vo)
{
    __shared__ float sWT[40][128];   // [i][j], j=0..119 valid (q|k|v), 120..127 zero
    __shared__ float sBias[128];
    __shared__ float sG[40], sBt[40];
    __shared__ float sX[64][41];
    __shared__ float sOut[64][129];

    const int tid = threadIdx.x;
    for (int idx = tid; idx < 5120; idx += 256) {
        int i = idx >> 7, j = idx & 127;
        float val = 0.f;
        if (j < 40)       val = Wq[i * 40 + j];
        else if (j < 80)  val = Wk[i * 40 + (j - 40)];
        else if (j < 120) val = Wv[i * 40 + (j - 80)];
        sWT[i][j] = val;
    }
    if (tid < 128) {
        int j = tid;
        float val = 0.f;
        if (j < 40)       val = bq[j];
        else if (j < 80)  val = bk[j - 40];
        else if (j < 120) val = bv[j - 80];
        sBias[j] = val;
    }
    if (tid < 40) { sG[tid] = g[tid]; sBt[tid] = be[tid]; }

    const float4* xblk = (const float4*)(x + (size_t)blockIdx.x * 64 * 40);
    for (int idx = tid; idx < 640; idx += 256) {
        float4 u = xblk[idx];
        int fl = idx * 4;
        int r = fl / 40, c = fl - r * 40;
        sX[r][c] = u.x; sX[r][c + 1] = u.y; sX[r][c + 2] = u.z; sX[r][c + 3] = u.w;
    }
    __syncthreads();

    const int lane = tid & 63;
    const int part = tid >> 6;
    const int j0 = part * 32;

    // fused LN stats: one LDS pass
    float s1 = 0.f, s2 = 0.f;
#pragma unroll 8
    for (int i = 0; i < 40; i++) { float v = sX[lane][i]; s1 += v; s2 += v * v; }
    const float mu = s1 * 0.025f;
    const float rs = rsqrtf(s2 * 0.025f - mu * mu + EPSF);

    float acc[32];
#pragma unroll
    for (int jj = 0; jj < 32; jj++) acc[jj] = sBias[j0 + jj];
#pragma unroll 4
    for (int i = 0; i < 40; i++) {
        const float hi = (sX[lane][i] - mu) * rs * sG[i] + sBt[i];
        const float4* wrow = (const float4*)&sWT[i][j0];
#pragma unroll
        for (int c = 0; c < 8; c++) {
            float4 wv = wrow[c];
            acc[c * 4 + 0] += hi * wv.x;
            acc[c * 4 + 1] += hi * wv.y;
            acc[c * 4 + 2] += hi * wv.z;
            acc[c * 4 + 3] += hi * wv.w;
        }
    }
#pragma unroll
    for (int jj = 0; jj < 32; jj++) sOut[lane][j0 + jj] = acc[jj];
    __syncthreads();

    const int row0 = blockIdx.x * 64;
    const int b4 = (row0 >> 9) * 4, s0 = row0 & 511;
    for (int fi = tid; fi < 2304; fi += 256) {
        int region = fi / 192;
        int kk = fi - region * 192;
        int w = region >> 2, hh = region & 3;
        int r = kk / 3, gg = kk - r * 3;
        int bj = w * 40 + hh * 10 + gg * 4;
        float4 val;
        val.x = sOut[r][bj];
        val.y = sOut[r][bj + 1];
        val.z = (gg == 2) ? 0.f : sOut[r][bj + 2];
        val.w = (gg == 2) ? 0.f : sOut[r][bj + 3];
        float* op = (w == 0) ? qo : (w == 1) ? ko : vo;
        *(float4*)(op + ((size_t)((b4 + hh) * 512 + s0 + r)) * DPP + gg * 4) = val;
    }
}

// ---------------- K2: attention v8 ----------------
// grid 256 = bh. block 512 = 8 waves = k-eighths (64 keys each).
// QPT=8: each lane holds 8 queries in registers. v8 fix: asm keep-alive
// on q[][] prevents the compiler from rematerializing the q global loads
// inside the kt loop (v7 allocated only 112 VGPRs and re-fetched q from
// L2 every iteration, ~1.3 GB of L2 traffic). Forces ~200 VGPR residency
// (legal at 2 waves/SIMD under launch_bounds(512,2)).
__global__ __launch_bounds__(512, 2) void k_attn(
    const float* __restrict__ qg, const float* __restrict__ kg,
    const float* __restrict__ vg, float* __restrict__ ctx)
{
    __shared__ float smem[24576];        // 96 KB
    float4* sK = (float4*)smem;          // [1536]
    float4* sV = sK + 1536;              // [1536]

    const int tid = threadIdx.x;
    const int bh = blockIdx.x;

    const float4* kp = (const float4*)(kg + (size_t)bh * 512 * DPP);
    const float4* vp = (const float4*)(vg + (size_t)bh * 512 * DPP);
    for (int idx = tid; idx < 1536; idx += 512) { sK[idx] = kp[idx]; sV[idx] = vp[idx]; }

    const int lane = tid & 63;
    const int wave = tid >> 6;           // k-eighth
    const int kbase = wave * 64;

    const float cscale = 1.4426950408889634f / 3.1622776601683795f;  // log2e/sqrt(10)
    v2f q[8][5];
#pragma unroll
    for (int jj = 0; jj < 8; jj++) {
        const float2* qp = (const float2*)(qg + ((size_t)bh * 512 + jj * 64 + lane) * DPP);
#pragma unroll
        for (int c = 0; c < 5; c++) {
            float2 u = qp[c];
            v2f t; t.x = u.x * cscale; t.y = u.y * cscale;
            q[jj][c] = t;
        }
    }
    // Pin q in VGPRs: opaque to rematerialization/sinking.
#pragma unroll
    for (int jj = 0; jj < 8; jj++)
#pragma unroll
        for (int c = 0; c < 5; c++)
            asm volatile("" : "+v"(q[jj][c]));

    __syncthreads();   // staging complete (q loads overlapped with it)

    float l[8];
    v2f a[8][5];
#pragma unroll
    for (int jj = 0; jj < 8; jj++) {
        l[jj] = 0.f;
#pragma unroll
        for (int d = 0; d < 5; d++) a[jj][d] = (v2f)(0.f);
    }

    for (int kt = 0; kt < 64; kt += 2) {
        const int ki = kbase + kt;
        const float4 ka0 = sK[ki * 3 + 0], ka1 = sK[ki * 3 + 1], ka2 = sK[ki * 3 + 2];
        const float4 kb0 = sK[ki * 3 + 3], kb1 = sK[ki * 3 + 4], kb2 = sK[ki * 3 + 5];
        const float4 va0 = sV[ki * 3 + 0], va1 = sV[ki * 3 + 1], va2 = sV[ki * 3 + 2];
        const float4 vb0 = sV[ki * 3 + 3], vb1 = sV[ki * 3 + 4], vb2 = sV[ki * 3 + 5];
        v2f ka[5], kb[5], va[5], vb[5];
        ka[0] = v2f{ka0.x, ka0.y}; ka[1] = v2f{ka0.z, ka0.w};
        ka[2] = v2f{ka1.x, ka1.y}; ka[3] = v2f{ka1.z, ka1.w};
        ka[4] = v2f{ka2.x, ka2.y};
        kb[0] = v2f{kb0.x, kb0.y}; kb[1] = v2f{kb0.z, kb0.w};
        kb[2] = v2f{kb1.x, kb1.y}; kb[3] = v2f{kb1.z, kb1.w};
        kb[4] = v2f{kb2.x, kb2.y};
        va[0] = v2f{va0.x, va0.y}; va[1] = v2f{va0.z, va0.w};
        va[2] = v2f{va1.x, va1.y}; va[3] = v2f{va1.z, va1.w};
        va[4] = v2f{va2.x, va2.y};
        vb[0] = v2f{vb0.x, vb0.y}; vb[1] = v2f{vb0.z, vb0.w};
        vb[2] = v2f{vb1.x, vb1.y}; vb[3] = v2f{vb1.z, vb1.w};
        vb[4] = v2f{vb2.x, vb2.y};
#pragma unroll
        for (int jj = 0; jj < 8; jj++) {
            v2f da = q[jj][0] * ka[0];
            v2f db = q[jj][0] * kb[0];
#pragma unroll
            for (int c = 1; c < 5; c++) {
                da += q[jj][c] * ka[c];
                db += q[jj][c] * kb[c];
            }
            const float pa = __builtin_amdgcn_exp2f(da.x + da.y);
            const float pb = __builtin_amdgcn_exp2f(db.x + db.y);
            l[jj] += pa + pb;
            const v2f pa2 = {pa, pa};
            const v2f pb2 = {pb, pb};
#pragma unroll
            for (int d = 0; d < 5; d++)
                a[jj][d] += pa2 * va[d] + pb2 * vb[d];
        }
    }
    __syncthreads();   // all sK/sV reads complete -> safe to alias

    // phase A: waves 0-3 write partial sets [w][q 0..511][12]  (96 KB)
    if (wave < 4) {
#pragma unroll
        for (int jj = 0; jj < 8; jj++) {
            float4* p = (float4*)(smem + ((wave * 512 + jj * 64 + lane) * 12));
            float4 u0, u1, u2;
            u0.x = a[jj][0].x; u0.y = a[jj][0].y; u0.z = a[jj][1].x; u0.w = a[jj][1].y;
            u1.x = a[jj][2].x; u1.y = a[jj][2].y; u1.z = a[jj][3].x; u1.w = a[jj][3].y;
            u2.x = a[jj][4].x; u2.y = a[jj][4].y; u2.z = l[jj];     u2.w = 0.f;
            p[0] = u0; p[1] = u1; p[2] = u2;
        }
    }
    __syncthreads();

    // phase B: waves 4-7 accumulate into set (wave-4)
    if (wave >= 4) {
        const int w = wave - 4;
#pragma unroll
        for (int jj = 0; jj < 8; jj++) {
            float4* p = (float4*)(smem + ((w * 512 + jj * 64 + lane) * 12));
            float4 u0 = p[0], u1 = p[1], u2 = p[2];
            u0.x += a[jj][0].x; u0.y += a[jj][0].y; u0.z += a[jj][1].x; u0.w += a[jj][1].y;
            u1.x += a[jj][2].x; u1.y += a[jj][2].y; u1.z += a[jj][3].x; u1.w += a[jj][3].y;
            u2.x += a[jj][4].x; u2.y += a[jj][4].y; u2.z += l[jj];
            p[0] = u0; p[1] = u1; p[2] = u2;
        }
    }
    __syncthreads();

    // merge: 512 threads, one query each over 4 sets
    {
        float acc[10], lt = 0.f;
#pragma unroll
        for (int d = 0; d < 10; d++) acc[d] = 0.f;
#pragma unroll
        for (int w = 0; w < 4; w++) {
            const float4* p = (const float4*)(smem + ((w * 512 + tid) * 12));
            float4 u0 = p[0], u1 = p[1], u2 = p[2];
            acc[0] += u0.x; acc[1] += u0.y; acc[2] += u0.z; acc[3] += u0.w;
            acc[4] += u1.x; acc[5] += u1.y; acc[6] += u1.z; acc[7] += u1.w;
            acc[8] += u2.x; acc[9] += u2.y; lt += u2.z;
        }
        const float inv = 1.f / lt;
        float* op = ctx + ((size_t)bh * 512 + tid) * 10;
#pragma unroll
        for (int d = 0; d < 5; d++) {
            float2 u; u.x = acc[d * 2] * inv; u.y = acc[d * 2 + 1] * inv;
            *(float2*)(op + d * 2) = u;
        }
    }
}

// ---------------- K3: Wo + residual + LN2 + FFN + residual ----------------
// grid 512 x 256. Block = 64 rows; wave = col-slice, lane = row.
__global__ __launch_bounds__(256) void k_out_ffn(
    const float* __restrict__ ctx, const float* __restrict__ x,
    const float* __restrict__ Wo, const float* __restrict__ bo,
    const float* __restrict__ g2, const float* __restrict__ bt2,
    const float* __restrict__ W1, const float* __restrict__ b1,
    const float* __restrict__ W2, const float* __restrict__ b2,
    float* __restrict__ out)
{
    __shared__ float sWo[40][48];
    __shared__ float sW1[40][32];
    __shared__ float sW2[20][48];
    __shared__ float sBo[40], sG2[40], sBt2[40], sB1[20], sB2[40];
    __shared__ float sCtx[64][41];
    __shared__ float sH[64][41];
    __shared__ float sIt[64][21];
    __shared__ float sSum[64][4], sSum2[64][4];

    const int tid = threadIdx.x;
    for (int idx = tid; idx < 1600; idx += 256) {
        int i = idx / 40, j = idx % 40;
        sWo[i][(j / 10) * 12 + (j % 10)] = Wo[idx];
    }
    for (int idx = tid; idx < 800; idx += 256) {
        {
            int i = idx / 20, j = idx % 20;
            sW1[i][(j / 5) * 8 + (j % 5)] = W1[idx];
        }
        {
            int i = idx / 40, j = idx % 40;
            sW2[i][(j / 10) * 12 + (j % 10)] = W2[idx];
        }
    }
    if (tid < 40) { sBo[tid] = bo[tid]; sG2[tid] = g2[tid]; sBt2[tid] = bt2[tid]; sB2[tid] = b2[tid]; }
    if (tid < 20) sB1[tid] = b1[tid];

    const int row0 = blockIdx.x * 64;
    const int b = row0 >> 9, s0 = row0 & 511;

    for (int idx = tid; idx < 640; idx += 256) {
        const int hh = idx / 160, f = idx - hh * 160;
        float4 u = *(const float4*)(ctx + ((size_t)((b * 4 + hh) * 512 + s0)) * 10 + f * 4);
        const int fo = f * 4;
        float e[4] = {u.x, u.y, u.z, u.w};
#pragma unroll
        for (int t = 0; t < 4; t++) {
            const int fe = fo + t;
            const int r = fe / 10, c = fe - r * 10;
            sCtx[r][hh * 10 + c] = e[t];
        }
    }
    const float4* xblk = (const float4*)(x + (size_t)blockIdx.x * 64 * 40);
    for (int idx = tid; idx < 640; idx += 256) {
        float4 w = xblk[idx];
        int fl = idx * 4;
        int r = fl / 40, c = fl - r * 40;
        sH[r][c] = w.x; sH[r][c + 1] = w.y; sH[r][c + 2] = w.z; sH[r][c + 3] = w.w;
    }
    __syncthreads();

    const int lane = tid & 63;
    const int wv = tid >> 6;
    const int j0 = wv * 10;

    float acc[10];
#pragma unroll
    for (int j = 0; j < 10; j++) acc[j] = sBo[j0 + j] + sH[lane][j0 + j];
#pragma unroll 8
    for (int i = 0; i < 40; i++) {
        const float ci = sCtx[lane][i];
        const float4* wrow = (const float4*)&sWo[i][wv * 12];
        float4 w0 = wrow[0], w1 = wrow[1], w2 = wrow[2];
        acc[0] += ci * w0.x; acc[1] += ci * w0.y; acc[2] += ci * w0.z; acc[3] += ci * w0.w;
        acc[4] += ci * w1.x; acc[5] += ci * w1.y; acc[6] += ci * w1.z; acc[7] += ci * w1.w;
        acc[8] += ci * w2.x; acc[9] += ci * w2.y;
    }
    {
        float s1 = 0.f, s2 = 0.f;
#pragma unroll
        for (int j = 0; j < 10; j++) { s1 += acc[j]; s2 += acc[j] * acc[j]; }
        sSum[lane][wv] = s1; sSum2[lane][wv] = s2;
    }
    __syncthreads();
    const float mu = (sSum[lane][0] + sSum[lane][1] + sSum[lane][2] + sSum[lane][3]) * 0.025f;
    const float ex2 = (sSum2[lane][0] + sSum2[lane][1] + sSum2[lane][2] + sSum2[lane][3]) * 0.025f;
    const float rs = rsqrtf(ex2 - mu * mu + EPSF);
#pragma unroll
    for (int j = 0; j < 10; j++)
        sH[lane][j0 + j] = (acc[j] - mu) * rs * sG2[j0 + j] + sBt2[j0 + j];
    __syncthreads();

    const int f0 = wv * 5;
    float it[5];
#pragma unroll
    for (int j = 0; j < 5; j++) it[j] = sB1[f0 + j];
#pragma unroll 8
    for (int i = 0; i < 40; i++) {
        const float hi = sH[lane][i];
        const float4* wrow = (const float4*)&sW1[i][wv * 8];
        float4 w0 = wrow[0], w1 = wrow[1];
        it[0] += hi * w0.x; it[1] += hi * w0.y; it[2] += hi * w0.z; it[3] += hi * w0.w;
        it[4] += hi * w1.x;
    }
#pragma unroll
    for (int j = 0; j < 5; j++) {
        float t = it[j];
        sIt[lane][f0 + j] = 0.5f * t * (1.0f + erff(t * 0.70710678118654752f));
    }
    __syncthreads();

    float o[10];
#pragma unroll
    for (int j = 0; j < 10; j++) o[j] = acc[j] + sB2[j0 + j];
#pragma unroll 4
    for (int i = 0; i < 20; i++) {
        const float ii = sIt[lane][i];
        const float4* wrow = (const float4*)&sW2[i][wv * 12];
        float4 w0 = wrow[0], w1 = wrow[1], w2 = wrow[2];
        o[0] += ii * w0.x; o[1] += ii * w0.y; o[2] += ii * w0.z; o[3] += ii * w0.w;
        o[4] += ii * w1.x; o[5] += ii * w1.y; o[6] += ii * w1.z; o[7] += ii * w1.w;
        o[8] += ii * w2.x; o[9] += ii * w2.y;
    }
#pragma unroll
    for (int j = 0; j < 10; j++) sCtx[lane][j0 + j] = o[j];
    __syncthreads();

    float4* oblk = (float4*)(out + (size_t)blockIdx.x * 64 * 40);
    for (int idx = tid; idx < 640; idx += 256) {
        int fl = idx * 4;
        int r = fl / 40, c = fl - r * 40;
        float4 u;
        u.x = sCtx[r][c]; u.y = sCtx[r][c + 1]; u.z = sCtx[r][c + 2]; u.w = sCtx[r][c + 3];
        oblk[idx] = u;
    }
}

extern "C" void kernel_launch(void* const* d_in, const int* in_sizes, int n_in,
                              void* d_out, int out_size, void* d_ws, size_t ws_size,
                              hipStream_t stream)
{
    const float* x   = (const float*)d_in[0];
    const float* g1  = (const float*)d_in[1];
    const float* be1 = (const float*)d_in[2];
    const float* Wq  = (const float*)d_in[3];
    const float* bq  = (const float*)d_in[4];
    const float* Wk  = (const float*)d_in[5];
    const float* bk  = (const float*)d_in[6];
    const float* Wv  = (const float*)d_in[7];
    const float* bv  = (const float*)d_in[8];
    const float* Wo  = (const float*)d_in[9];
    const float* bo  = (const float*)d_in[10];
    const float* g2  = (const float*)d_in[11];
    const float* bt2 = (const float*)d_in[12];
    const float* W1  = (const float*)d_in[13];
    const float* b1  = (const float*)d_in[14];
    const float* W2  = (const float*)d_in[15];
    const float* b2  = (const float*)d_in[16];

    float* ws = (float*)d_ws;
    const size_t QKV = (size_t)BB * 4 * SS * DPP;  // 1,572,864 floats
    float* q   = ws;
    float* k   = ws + QKV;
    float* v   = ws + 2 * QKV;
    float* ctx = ws + 3 * QKV;  // [B,H,S,10] = 1,310,720 floats

    k_ln_qkv<<<512, 256, 0, stream>>>(x, g1, be1, Wq, bq, Wk, bk, Wv, bv, q, k, v);
    k_attn<<<256, 512, 0, stream>>>(q, k, v, ctx);
    k_out_ffn<<<512, 256, 0, stream>>>(ctx, x, Wo, bo, g2, bt2, W1, b1, W2, b2,
                                       (float*)d_out);
}

// Round 3
// 167.170 us; speedup vs baseline: 1.0042x; 1.0042x over previous
//
#include <hip/hip_runtime.h>
#include <stdint.h>

#define BB 64
#define SS 512
#define DPP 12   // padded head dim (48B rows -> float4 aligned)
#define EPSF 1e-5f

typedef float v2f __attribute__((ext_vector_type(2)));

// ---------------- K1: LN1 + QKV projection ----------------
// grid 512 x 256. Block = 64 rows; wave = j-part (32 cols), lane = row.
__global__ __launch_bounds__(256) void k_ln_qkv(
    const float* __restrict__ x, const float* __restrict__ g, const float* __restrict__ be,
    const float* __restrict__ Wq, const float* __restrict__ bq,
    const float* __restrict__ Wk, const float* __restrict__ bk,
    const float* __restrict__ Wv, const float* __restrict__ bv,
    float* __restrict__ qo, float* __restrict__ ko, float* __restrict__ vo)
{
    __shared__ float sWT[40][128];   // [i][j], j=0..119 valid (q|k|v), 120..127 zero
    __shared__ float sBias[128];
    __shared__ float sG[40], sBt[40];
    __shared__ float sX[64][41];
    __shared__ float sOut[64][129];

    const int tid = threadIdx.x;
    for (int idx = tid; idx < 5120; idx += 256) {
        int i = idx >> 7, j = idx & 127;
        float val = 0.f;
        if (j < 40)       val = Wq[i * 40 + j];
        else if (j < 80)  val = Wk[i * 40 + (j - 40)];
        else if (j < 120) val = Wv[i * 40 + (j - 80)];
        sWT[i][j] = val;
    }
    if (tid < 128) {
        int j = tid;
        float val = 0.f;
        if (j < 40)       val = bq[j];
        else if (j < 80)  val = bk[j - 40];
        else if (j < 120) val = bv[j - 80];
        sBias[j] = val;
    }
    if (tid < 40) { sG[tid] = g[tid]; sBt[tid] = be[tid]; }

    const float4* xblk = (const float4*)(x + (size_t)blockIdx.x * 64 * 40);
    for (int idx = tid; idx < 640; idx += 256) {
        float4 u = xblk[idx];
        int fl = idx * 4;
        int r = fl / 40, c = fl - r * 40;
        sX[r][c] = u.x; sX[r][c + 1] = u.y; sX[r][c + 2] = u.z; sX[r][c + 3] = u.w;
    }
    __syncthreads();

    const int lane = tid & 63;
    const int part = tid >> 6;
    const int j0 = part * 32;

    // fused LN stats: one LDS pass
    float s1 = 0.f, s2 = 0.f;
#pragma unroll 8
    for (int i = 0; i < 40; i++) { float v = sX[lane][i]; s1 += v; s2 += v * v; }
    const float mu = s1 * 0.025f;
    const float rs = rsqrtf(s2 * 0.025f - mu * mu + EPSF);

    float acc[32];
#pragma unroll
    for (int jj = 0; jj < 32; jj++) acc[jj] = sBias[j0 + jj];
#pragma unroll 4
    for (int i = 0; i < 40; i++) {
        const float hi = (sX[lane][i] - mu) * rs * sG[i] + sBt[i];
        const float4* wrow = (const float4*)&sWT[i][j0];
#pragma unroll
        for (int c = 0; c < 8; c++) {
            float4 wv = wrow[c];
            acc[c * 4 + 0] += hi * wv.x;
            acc[c * 4 + 1] += hi * wv.y;
            acc[c * 4 + 2] += hi * wv.z;
            acc[c * 4 + 3] += hi * wv.w;
        }
    }
#pragma unroll
    for (int jj = 0; jj < 32; jj++) sOut[lane][j0 + jj] = acc[jj];
    __syncthreads();

    const int row0 = blockIdx.x * 64;
    const int b4 = (row0 >> 9) * 4, s0 = row0 & 511;
    for (int fi = tid; fi < 2304; fi += 256) {
        int region = fi / 192;
        int kk = fi - region * 192;
        int w = region >> 2, hh = region & 3;
        int r = kk / 3, gg = kk - r * 3;
        int bj = w * 40 + hh * 10 + gg * 4;
        float4 val;
        val.x = sOut[r][bj];
        val.y = sOut[r][bj + 1];
        val.z = (gg == 2) ? 0.f : sOut[r][bj + 2];
        val.w = (gg == 2) ? 0.f : sOut[r][bj + 3];
        float* op = (w == 0) ? qo : (w == 1) ? ko : vo;
        *(float4*)(op + ((size_t)((b4 + hh) * 512 + s0 + r)) * DPP + gg * 4) = val;
    }
}

// ---------------- K2: attention v9 ----------------
// grid 256 = bh. block 512 = 8 waves = k-eighths (64 keys each).
// QPT=8: each lane holds 8 queries in registers. v9 fix: v8's keep-alive
// forced q liveness but regalloc still targeted a 4-waves/SIMD budget
// (VGPR_Count=112 < the ~200 needed) and spilled q to scratch, reloading
// it every kt iteration. amdgpu_waves_per_eu(2,2) pins the occupancy
// window to exactly 2 waves/SIMD -> 256-VGPR budget -> q+a+l resident.
__global__ __launch_bounds__(512, 2)
__attribute__((amdgpu_waves_per_eu(2, 2)))
void k_attn(
    const float* __restrict__ qg, const float* __restrict__ kg,
    const float* __restrict__ vg, float* __restrict__ ctx)
{
    __shared__ float smem[24576];        // 96 KB
    float4* sK = (float4*)smem;          // [1536]
    float4* sV = sK + 1536;              // [1536]

    const int tid = threadIdx.x;
    const int bh = blockIdx.x;

    const float4* kp = (const float4*)(kg + (size_t)bh * 512 * DPP);
    const float4* vp = (const float4*)(vg + (size_t)bh * 512 * DPP);
    for (int idx = tid; idx < 1536; idx += 512) { sK[idx] = kp[idx]; sV[idx] = vp[idx]; }

    const int lane = tid & 63;
    const int wave = tid >> 6;           // k-eighth
    const int kbase = wave * 64;

    const float cscale = 1.4426950408889634f / 3.1622776601683795f;  // log2e/sqrt(10)
    v2f q[8][5];
#pragma unroll
    for (int jj = 0; jj < 8; jj++) {
        const float2* qp = (const float2*)(qg + ((size_t)bh * 512 + jj * 64 + lane) * DPP);
#pragma unroll
        for (int c = 0; c < 5; c++) {
            float2 u = qp[c];
            v2f t; t.x = u.x * cscale; t.y = u.y * cscale;
            q[jj][c] = t;
        }
    }
    // Pin q in VGPRs: opaque to rematerialization/sinking.
#pragma unroll
    for (int jj = 0; jj < 8; jj++)
#pragma unroll
        for (int c = 0; c < 5; c++)
            asm volatile("" : "+v"(q[jj][c]));

    __syncthreads();   // staging complete (q loads overlapped with it)

    float l[8];
    v2f a[8][5];
#pragma unroll
    for (int jj = 0; jj < 8; jj++) {
        l[jj] = 0.f;
#pragma unroll
        for (int d = 0; d < 5; d++) a[jj][d] = (v2f)(0.f);
    }

    for (int kt = 0; kt < 64; kt += 2) {
        const int ki = kbase + kt;
        const float4 ka0 = sK[ki * 3 + 0], ka1 = sK[ki * 3 + 1], ka2 = sK[ki * 3 + 2];
        const float4 kb0 = sK[ki * 3 + 3], kb1 = sK[ki * 3 + 4], kb2 = sK[ki * 3 + 5];
        const float4 va0 = sV[ki * 3 + 0], va1 = sV[ki * 3 + 1], va2 = sV[ki * 3 + 2];
        const float4 vb0 = sV[ki * 3 + 3], vb1 = sV[ki * 3 + 4], vb2 = sV[ki * 3 + 5];
        v2f ka[5], kb[5], va[5], vb[5];
        ka[0] = v2f{ka0.x, ka0.y}; ka[1] = v2f{ka0.z, ka0.w};
        ka[2] = v2f{ka1.x, ka1.y}; ka[3] = v2f{ka1.z, ka1.w};
        ka[4] = v2f{ka2.x, ka2.y};
        kb[0] = v2f{kb0.x, kb0.y}; kb[1] = v2f{kb0.z, kb0.w};
        kb[2] = v2f{kb1.x, kb1.y}; kb[3] = v2f{kb1.z, kb1.w};
        kb[4] = v2f{kb2.x, kb2.y};
        va[0] = v2f{va0.x, va0.y}; va[1] = v2f{va0.z, va0.w};
        va[2] = v2f{va1.x, va1.y}; va[3] = v2f{va1.z, va1.w};
        va[4] = v2f{va2.x, va2.y};
        vb[0] = v2f{vb0.x, vb0.y}; vb[1] = v2f{vb0.z, vb0.w};
        vb[2] = v2f{vb1.x, vb1.y}; vb[3] = v2f{vb1.z, vb1.w};
        vb[4] = v2f{vb2.x, vb2.y};
#pragma unroll
        for (int jj = 0; jj < 8; jj++) {
            v2f da = q[jj][0] * ka[0];
            v2f db = q[jj][0] * kb[0];
#pragma unroll
            for (int c = 1; c < 5; c++) {
                da += q[jj][c] * ka[c];
                db += q[jj][c] * kb[c];
            }
            const float pa = __builtin_amdgcn_exp2f(da.x + da.y);
            const float pb = __builtin_amdgcn_exp2f(db.x + db.y);
            l[jj] += pa + pb;
            const v2f pa2 = {pa, pa};
            const v2f pb2 = {pb, pb};
#pragma unroll
            for (int d = 0; d < 5; d++)
                a[jj][d] += pa2 * va[d] + pb2 * vb[d];
        }
    }
    __syncthreads();   // all sK/sV reads complete -> safe to alias

    // phase A: waves 0-3 write partial sets [w][q 0..511][12]  (96 KB)
    if (wave < 4) {
#pragma unroll
        for (int jj = 0; jj < 8; jj++) {
            float4* p = (float4*)(smem + ((wave * 512 + jj * 64 + lane) * 12));
            float4 u0, u1, u2;
            u0.x = a[jj][0].x; u0.y = a[jj][0].y; u0.z = a[jj][1].x; u0.w = a[jj][1].y;
            u1.x = a[jj][2].x; u1.y = a[jj][2].y; u1.z = a[jj][3].x; u1.w = a[jj][3].y;
            u2.x = a[jj][4].x; u2.y = a[jj][4].y; u2.z = l[jj];     u2.w = 0.f;
            p[0] = u0; p[1] = u1; p[2] = u2;
        }
    }
    __syncthreads();

    // phase B: waves 4-7 accumulate into set (wave-4)
    if (wave >= 4) {
        const int w = wave - 4;
#pragma unroll
        for (int jj = 0; jj < 8; jj++) {
            float4* p = (float4*)(smem + ((w * 512 + jj * 64 + lane) * 12));
            float4 u0 = p[0], u1 = p[1], u2 = p[2];
            u0.x += a[jj][0].x; u0.y += a[jj][0].y; u0.z += a[jj][1].x; u0.w += a[jj][1].y;
            u1.x += a[jj][2].x; u1.y += a[jj][2].y; u1.z += a[jj][3].x; u1.w += a[jj][3].y;
            u2.x += a[jj][4].x; u2.y += a[jj][4].y; u2.z += l[jj];
            p[0] = u0; p[1] = u1; p[2] = u2;
        }
    }
    __syncthreads();

    // merge: 512 threads, one query each over 4 sets
    {
        float acc[10], lt = 0.f;
#pragma unroll
        for (int d = 0; d < 10; d++) acc[d] = 0.f;
#pragma unroll
        for (int w = 0; w < 4; w++) {
            const float4* p = (const float4*)(smem + ((w * 512 + tid) * 12));
            float4 u0 = p[0], u1 = p[1], u2 = p[2];
            acc[0] += u0.x; acc[1] += u0.y; acc[2] += u0.z; acc[3] += u0.w;
            acc[4] += u1.x; acc[5] += u1.y; acc[6] += u1.z; acc[7] += u1.w;
            acc[8] += u2.x; acc[9] += u2.y; lt += u2.z;
        }
        const float inv = 1.f / lt;
        float* op = ctx + ((size_t)bh * 512 + tid) * 10;
#pragma unroll
        for (int d = 0; d < 5; d++) {
            float2 u; u.x = acc[d * 2] * inv; u.y = acc[d * 2 + 1] * inv;
            *(float2*)(op + d * 2) = u;
        }
    }
}

// ---------------- K3: Wo + residual + LN2 + FFN + residual ----------------
// grid 512 x 256. Block = 64 rows; wave = col-slice, lane = row.
__global__ __launch_bounds__(256) void k_out_ffn(
    const float* __restrict__ ctx, const float* __restrict__ x,
    const float* __restrict__ Wo, const float* __restrict__ bo,
    const float* __restrict__ g2, const float* __restrict__ bt2,
    const float* __restrict__ W1, const float* __restrict__ b1,
    const float* __restrict__ W2, const float* __restrict__ b2,
    float* __restrict__ out)
{
    __shared__ float sWo[40][48];
    __shared__ float sW1[40][32];
    __shared__ float sW2[20][48];
    __shared__ float sBo[40], sG2[40], sBt2[40], sB1[20], sB2[40];
    __shared__ float sCtx[64][41];
    __shared__ float sH[64][41];
    __shared__ float sIt[64][21];
    __shared__ float sSum[64][4], sSum2[64][4];

    const int tid = threadIdx.x;
    for (int idx = tid; idx < 1600; idx += 256) {
        int i = idx / 40, j = idx % 40;
        sWo[i][(j / 10) * 12 + (j % 10)] = Wo[idx];
    }
    for (int idx = tid; idx < 800; idx += 256) {
        {
            int i = idx / 20, j = idx % 20;
            sW1[i][(j / 5) * 8 + (j % 5)] = W1[idx];
        }
        {
            int i = idx / 40, j = idx % 40;
            sW2[i][(j / 10) * 12 + (j % 10)] = W2[idx];
        }
    }
    if (tid < 40) { sBo[tid] = bo[tid]; sG2[tid] = g2[tid]; sBt2[tid] = bt2[tid]; sB2[tid] = b2[tid]; }
    if (tid < 20) sB1[tid] = b1[tid];

    const int row0 = blockIdx.x * 64;
    const int b = row0 >> 9, s0 = row0 & 511;

    for (int idx = tid; idx < 640; idx += 256) {
        const int hh = idx / 160, f = idx - hh * 160;
        float4 u = *(const float4*)(ctx + ((size_t)((b * 4 + hh) * 512 + s0)) * 10 + f * 4);
        const int fo = f * 4;
        float e[4] = {u.x, u.y, u.z, u.w};
#pragma unroll
        for (int t = 0; t < 4; t++) {
            const int fe = fo + t;
            const int r = fe / 10, c = fe - r * 10;
            sCtx[r][hh * 10 + c] = e[t];
        }
    }
    const float4* xblk = (const float4*)(x + (size_t)blockIdx.x * 64 * 40);
    for (int idx = tid; idx < 640; idx += 256) {
        float4 w = xblk[idx];
        int fl = idx * 4;
        int r = fl / 40, c = fl - r * 40;
        sH[r][c] = w.x; sH[r][c + 1] = w.y; sH[r][c + 2] = w.z; sH[r][c + 3] = w.w;
    }
    __syncthreads();

    const int lane = tid & 63;
    const int wv = tid >> 6;
    const int j0 = wv * 10;

    float acc[10];
#pragma unroll
    for (int j = 0; j < 10; j++) acc[j] = sBo[j0 + j] + sH[lane][j0 + j];
#pragma unroll 8
    for (int i = 0; i < 40; i++) {
        const float ci = sCtx[lane][i];
        const float4* wrow = (const float4*)&sWo[i][wv * 12];
        float4 w0 = wrow[0], w1 = wrow[1], w2 = wrow[2];
        acc[0] += ci * w0.x; acc[1] += ci * w0.y; acc[2] += ci * w0.z; acc[3] += ci * w0.w;
        acc[4] += ci * w1.x; acc[5] += ci * w1.y; acc[6] += ci * w1.z; acc[7] += ci * w1.w;
        acc[8] += ci * w2.x; acc[9] += ci * w2.y;
    }
    {
        float s1 = 0.f, s2 = 0.f;
#pragma unroll
        for (int j = 0; j < 10; j++) { s1 += acc[j]; s2 += acc[j] * acc[j]; }
        sSum[lane][wv] = s1; sSum2[lane][wv] = s2;
    }
    __syncthreads();
    const float mu = (sSum[lane][0] + sSum[lane][1] + sSum[lane][2] + sSum[lane][3]) * 0.025f;
    const float ex2 = (sSum2[lane][0] + sSum2[lane][1] + sSum2[lane][2] + sSum2[lane][3]) * 0.025f;
    const float rs = rsqrtf(ex2 - mu * mu + EPSF);
#pragma unroll
    for (int j = 0; j < 10; j++)
        sH[lane][j0 + j] = (acc[j] - mu) * rs * sG2[j0 + j] + sBt2[j0 + j];
    __syncthreads();

    const int f0 = wv * 5;
    float it[5];
#pragma unroll
    for (int j = 0; j < 5; j++) it[j] = sB1[f0 + j];
#pragma unroll 8
    for (int i = 0; i < 40; i++) {
        const float hi = sH[lane][i];
        const float4* wrow = (const float4*)&sW1[i][wv * 8];
        float4 w0 = wrow[0], w1 = wrow[1];
        it[0] += hi * w0.x; it[1] += hi * w0.y; it[2] += hi * w0.z; it[3] += hi * w0.w;
        it[4] += hi * w1.x;
    }
#pragma unroll
    for (int j = 0; j < 5; j++) {
        float t = it[j];
        sIt[lane][f0 + j] = 0.5f * t * (1.0f + erff(t * 0.70710678118654752f));
    }
    __syncthreads();

    float o[10];
#pragma unroll
    for (int j = 0; j < 10; j++) o[j] = acc[j] + sB2[j0 + j];
#pragma unroll 4
    for (int i = 0; i < 20; i++) {
        const float ii = sIt[lane][i];
        const float4* wrow = (const float4*)&sW2[i][wv * 12];
        float4 w0 = wrow[0], w1 = wrow[1], w2 = wrow[2];
        o[0] += ii * w0.x; o[1] += ii * w0.y; o[2] += ii * w0.z; o[3] += ii * w0.w;
        o[4] += ii * w1.x; o[5] += ii * w1.y; o[6] += ii * w1.z; o[7] += ii * w1.w;
        o[8] += ii * w2.x; o[9] += ii * w2.y;
    }
#pragma unroll
    for (int j = 0; j < 10; j++) sCtx[lane][j0 + j] = o[j];
    __syncthreads();

    float4* oblk = (float4*)(out + (size_t)blockIdx.x * 64 * 40);
    for (int idx = tid; idx < 640; idx += 256) {
        int fl = idx * 4;
        int r = fl / 40, c = fl - r * 40;
        float4 u;
        u.x = sCtx[r][c]; u.y = sCtx[r][c + 1]; u.z = sCtx[r][c + 2]; u.w = sCtx[r][c + 3];
        oblk[idx] = u;
    }
}

extern "C" void kernel_launch(void* const* d_in, const int* in_sizes, int n_in,
                              void* d_out, int out_size, void* d_ws, size_t ws_size,
                              hipStream_t stream)
{
    const float* x   = (const float*)d_in[0];
    const float* g1  = (const float*)d_in[1];
    const float* be1 = (const float*)d_in[2];
    const float* Wq  = (const float*)d_in[3];
    const float* bq  = (const float*)d_in[4];
    const float* Wk  = (const float*)d_in[5];
    const float* bk  = (const float*)d_in[6];
    const float* Wv  = (const float*)d_in[7];
    const float* bv  = (const float*)d_in[8];
    const float* Wo  = (const float*)d_in[9];
    const float* bo  = (const float*)d_in[10];
    const float* g2  = (const float*)d_in[11];
    const float* bt2 = (const float*)d_in[12];
    const float* W1  = (const float*)d_in[13];
    const float* b1  = (const float*)d_in[14];
    const float* W2  = (const float*)d_in[15];
    const float* b2  = (const float*)d_in[16];

    float* ws = (float*)d_ws;
    const size_t QKV = (size_t)BB * 4 * SS * DPP;  // 1,572,864 floats
    float* q   = ws;
    float* k   = ws + QKV;
    float* v   = ws + 2 * QKV;
    float* ctx = ws + 3 * QKV;  // [B,H,S,10] = 1,310,720 floats

    k_ln_qkv<<<512, 256, 0, stream>>>(x, g1, be1, Wq, bq, Wk, bk, Wv, bv, q, k, v);
    k_attn<<<256, 512, 0, stream>>>(q, k, v, ctx);
    k_out_ffn<<<512, 256, 0, stream>>>(ctx, x, Wo, bo, g2, bt2, W1, b1, W2, b2,
                                       (float*)d_out);
}

// Round 4
// 166.053 us; speedup vs baseline: 1.0110x; 1.0067x over previous
//
#include <hip/hip_runtime.h>
#include <stdint.h>

#define BB 64
#define SS 512
#define DPP 12   // padded head dim (48B rows -> float4 aligned)
#define EPSF 1e-5f

typedef float v2f __attribute__((ext_vector_type(2)));

// ---------------- K1: LN1 + QKV projection ----------------
// grid 512 x 256. Block = 64 rows; wave = j-part (32 cols), lane = row.
__global__ __launch_bounds__(256) void k_ln_qkv(
    const float* __restrict__ x, const float* __restrict__ g, const float* __restrict__ be,
    const float* __restrict__ Wq, const float* __restrict__ bq,
    const float* __restrict__ Wk, const float* __restrict__ bk,
    const float* __restrict__ Wv, const float* __restrict__ bv,
    float* __restrict__ qo, float* __restrict__ ko, float* __restrict__ vo)
{
    __shared__ float sWT[40][128];   // [i][j], j=0..119 valid (q|k|v), 120..127 zero
    __shared__ float sBias[128];
    __shared__ float sG[40], sBt[40];
    __shared__ float sX[64][41];
    __shared__ float sOut[64][129];

    const int tid = threadIdx.x;
    for (int idx = tid; idx < 5120; idx += 256) {
        int i = idx >> 7, j = idx & 127;
        float val = 0.f;
        if (j < 40)       val = Wq[i * 40 + j];
        else if (j < 80)  val = Wk[i * 40 + (j - 40)];
        else if (j < 120) val = Wv[i * 40 + (j - 80)];
        sWT[i][j] = val;
    }
    if (tid < 128) {
        int j = tid;
        float val = 0.f;
        if (j < 40)       val = bq[j];
        else if (j < 80)  val = bk[j - 40];
        else if (j < 120) val = bv[j - 80];
        sBias[j] = val;
    }
    if (tid < 40) { sG[tid] = g[tid]; sBt[tid] = be[tid]; }

    const float4* xblk = (const float4*)(x + (size_t)blockIdx.x * 64 * 40);
    for (int idx = tid; idx < 640; idx += 256) {
        float4 u = xblk[idx];
        int fl = idx * 4;
        int r = fl / 40, c = fl - r * 40;
        sX[r][c] = u.x; sX[r][c + 1] = u.y; sX[r][c + 2] = u.z; sX[r][c + 3] = u.w;
    }
    __syncthreads();

    const int lane = tid & 63;
    const int part = tid >> 6;
    const int j0 = part * 32;

    // fused LN stats: one LDS pass
    float s1 = 0.f, s2 = 0.f;
#pragma unroll 8
    for (int i = 0; i < 40; i++) { float v = sX[lane][i]; s1 += v; s2 += v * v; }
    const float mu = s1 * 0.025f;
    const float rs = rsqrtf(s2 * 0.025f - mu * mu + EPSF);

    float acc[32];
#pragma unroll
    for (int jj = 0; jj < 32; jj++) acc[jj] = sBias[j0 + jj];
#pragma unroll 4
    for (int i = 0; i < 40; i++) {
        const float hi = (sX[lane][i] - mu) * rs * sG[i] + sBt[i];
        const float4* wrow = (const float4*)&sWT[i][j0];
#pragma unroll
        for (int c = 0; c < 8; c++) {
            float4 wv = wrow[c];
            acc[c * 4 + 0] += hi * wv.x;
            acc[c * 4 + 1] += hi * wv.y;
            acc[c * 4 + 2] += hi * wv.z;
            acc[c * 4 + 3] += hi * wv.w;
        }
    }
#pragma unroll
    for (int jj = 0; jj < 32; jj++) sOut[lane][j0 + jj] = acc[jj];
    __syncthreads();

    const int row0 = blockIdx.x * 64;
    const int b4 = (row0 >> 9) * 4, s0 = row0 & 511;
    for (int fi = tid; fi < 2304; fi += 256) {
        int region = fi / 192;
        int kk = fi - region * 192;
        int w = region >> 2, hh = region & 3;
        int r = kk / 3, gg = kk - r * 3;
        int bj = w * 40 + hh * 10 + gg * 4;
        float4 val;
        val.x = sOut[r][bj];
        val.y = sOut[r][bj + 1];
        val.z = (gg == 2) ? 0.f : sOut[r][bj + 2];
        val.w = (gg == 2) ? 0.f : sOut[r][bj + 3];
        float* op = (w == 0) ? qo : (w == 1) ? ko : vo;
        *(float4*)(op + ((size_t)((b4 + hh) * 512 + s0 + r)) * DPP + gg * 4) = val;
    }
}

// ---------------- K2: attention v10 ----------------
// grid 512 = bh x q-half. block 256 = 4 waves = k-quarters (128 keys).
// QPT=4: q[4][5]+a[4][5]+l[4] = 84 persistent VGPRs -- fits the ~112
// budget the allocator insists on (v7-v9: QPT=8 needed 168 and it
// spilled/remat'd at identical ~51us regardless of attributes).
// Broadcast amortization x4; LDS volume halves vs v6. K-phase and
// V-phase separated to cap peak register temps.
__global__ __launch_bounds__(256, 2) void k_attn(
    const float* __restrict__ qg, const float* __restrict__ kg,
    const float* __restrict__ vg, float* __restrict__ ctx)
{
    __shared__ float smem[12288];        // 48 KB: sK+sV, aliased as partials
    float4* sK = (float4*)smem;          // [1536]
    float4* sV = sK + 1536;              // [1536]

    const int tid = threadIdx.x;
    const int bh = blockIdx.x >> 1;
    const int qh = blockIdx.x & 1;       // q-half

    const float4* kp = (const float4*)(kg + (size_t)bh * 512 * DPP);
    const float4* vp = (const float4*)(vg + (size_t)bh * 512 * DPP);
    for (int idx = tid; idx < 1536; idx += 256) { sK[idx] = kp[idx]; sV[idx] = vp[idx]; }

    const int lane = tid & 63;
    const int wave = tid >> 6;           // k-quarter
    const int kbase = wave * 128;

    const float cscale = 1.4426950408889634f / 3.1622776601683795f;  // log2e/sqrt(10)
    v2f q[4][5];
#pragma unroll
    for (int jj = 0; jj < 4; jj++) {
        const float2* qp = (const float2*)(qg + ((size_t)bh * 512 + qh * 256 + jj * 64 + lane) * DPP);
#pragma unroll
        for (int c = 0; c < 5; c++) {
            float2 u = qp[c];
            v2f t; t.x = u.x * cscale; t.y = u.y * cscale;
            q[jj][c] = t;
        }
    }
    // Pin q in VGPRs (opaque to remat/sinking).
#pragma unroll
    for (int jj = 0; jj < 4; jj++)
#pragma unroll
        for (int c = 0; c < 5; c++)
            asm volatile("" : "+v"(q[jj][c]));

    __syncthreads();   // staging complete (q loads overlapped with it)

    float l[4];
    v2f a[4][5];
#pragma unroll
    for (int jj = 0; jj < 4; jj++) {
        l[jj] = 0.f;
#pragma unroll
        for (int d = 0; d < 5; d++) a[jj][d] = (v2f)(0.f);
    }

    for (int kt = 0; kt < 128; kt += 2) {
        const int ki = kbase + kt;
        // ---- K phase: load 2 key rows, compute 8 logits -> probs ----
        const float4 ka0 = sK[ki * 3 + 0], ka1 = sK[ki * 3 + 1], ka2 = sK[ki * 3 + 2];
        const float4 kb0 = sK[ki * 3 + 3], kb1 = sK[ki * 3 + 4], kb2 = sK[ki * 3 + 5];
        v2f ka[5], kb[5];
        ka[0] = v2f{ka0.x, ka0.y}; ka[1] = v2f{ka0.z, ka0.w};
        ka[2] = v2f{ka1.x, ka1.y}; ka[3] = v2f{ka1.z, ka1.w};
        ka[4] = v2f{ka2.x, ka2.y};
        kb[0] = v2f{kb0.x, kb0.y}; kb[1] = v2f{kb0.z, kb0.w};
        kb[2] = v2f{kb1.x, kb1.y}; kb[3] = v2f{kb1.z, kb1.w};
        kb[4] = v2f{kb2.x, kb2.y};
        float pa[4], pb[4];
#pragma unroll
        for (int jj = 0; jj < 4; jj++) {
            v2f da = q[jj][0] * ka[0];
            v2f db = q[jj][0] * kb[0];
#pragma unroll
            for (int c = 1; c < 5; c++) {
                da += q[jj][c] * ka[c];
                db += q[jj][c] * kb[c];
            }
            pa[jj] = __builtin_amdgcn_exp2f(da.x + da.y);
            pb[jj] = __builtin_amdgcn_exp2f(db.x + db.y);
            l[jj] += pa[jj] + pb[jj];
        }
        // ---- V phase: load 2 value rows, accumulate PV ----
        const float4 va0 = sV[ki * 3 + 0], va1 = sV[ki * 3 + 1], va2 = sV[ki * 3 + 2];
        const float4 vb0 = sV[ki * 3 + 3], vb1 = sV[ki * 3 + 4], vb2 = sV[ki * 3 + 5];
        v2f va[5], vb[5];
        va[0] = v2f{va0.x, va0.y}; va[1] = v2f{va0.z, va0.w};
        va[2] = v2f{va1.x, va1.y}; va[3] = v2f{va1.z, va1.w};
        va[4] = v2f{va2.x, va2.y};
        vb[0] = v2f{vb0.x, vb0.y}; vb[1] = v2f{vb0.z, vb0.w};
        vb[2] = v2f{vb1.x, vb1.y}; vb[3] = v2f{vb1.z, vb1.w};
        vb[4] = v2f{vb2.x, vb2.y};
#pragma unroll
        for (int jj = 0; jj < 4; jj++) {
            const v2f pa2 = {pa[jj], pa[jj]};
            const v2f pb2 = {pb[jj], pb[jj]};
#pragma unroll
            for (int d = 0; d < 5; d++)
                a[jj][d] += pa2 * va[d] + pb2 * vb[d];
        }
    }
    __syncthreads();   // all sK/sV reads complete -> safe to alias

    // partial sets: [set 0..1][q-local 0..255][12]; 24 KB aliased over sK/sV
    // phase A: waves 0,1 write sets 0,1
    if (wave < 2) {
#pragma unroll
        for (int jj = 0; jj < 4; jj++) {
            float4* p = (float4*)(smem + ((wave * 256 + jj * 64 + lane) * 12));
            float4 u0, u1, u2;
            u0.x = a[jj][0].x; u0.y = a[jj][0].y; u0.z = a[jj][1].x; u0.w = a[jj][1].y;
            u1.x = a[jj][2].x; u1.y = a[jj][2].y; u1.z = a[jj][3].x; u1.w = a[jj][3].y;
            u2.x = a[jj][4].x; u2.y = a[jj][4].y; u2.z = l[jj];     u2.w = 0.f;
            p[0] = u0; p[1] = u1; p[2] = u2;
        }
    }
    __syncthreads();

    // phase B: waves 2,3 accumulate into set (wave-2)
    if (wave >= 2) {
        const int w = wave - 2;
#pragma unroll
        for (int jj = 0; jj < 4; jj++) {
            float4* p = (float4*)(smem + ((w * 256 + jj * 64 + lane) * 12));
            float4 u0 = p[0], u1 = p[1], u2 = p[2];
            u0.x += a[jj][0].x; u0.y += a[jj][0].y; u0.z += a[jj][1].x; u0.w += a[jj][1].y;
            u1.x += a[jj][2].x; u1.y += a[jj][2].y; u1.z += a[jj][3].x; u1.w += a[jj][3].y;
            u2.x += a[jj][4].x; u2.y += a[jj][4].y; u2.z += l[jj];
            p[0] = u0; p[1] = u1; p[2] = u2;
        }
    }
    __syncthreads();

    // merge: 256 threads, one query each over 2 sets
    {
        float acc[10], lt = 0.f;
#pragma unroll
        for (int d = 0; d < 10; d++) acc[d] = 0.f;
#pragma unroll
        for (int w = 0; w < 2; w++) {
            const float4* p = (const float4*)(smem + ((w * 256 + tid) * 12));
            float4 u0 = p[0], u1 = p[1], u2 = p[2];
            acc[0] += u0.x; acc[1] += u0.y; acc[2] += u0.z; acc[3] += u0.w;
            acc[4] += u1.x; acc[5] += u1.y; acc[6] += u1.z; acc[7] += u1.w;
            acc[8] += u2.x; acc[9] += u2.y; lt += u2.z;
        }
        const float inv = 1.f / lt;
        float* op = ctx + ((size_t)bh * 512 + qh * 256 + tid) * 10;
#pragma unroll
        for (int d = 0; d < 5; d++) {
            float2 u; u.x = acc[d * 2] * inv; u.y = acc[d * 2 + 1] * inv;
            *(float2*)(op + d * 2) = u;
        }
    }
}

// ---------------- K3: Wo + residual + LN2 + FFN + residual ----------------
// grid 512 x 256. Block = 64 rows; wave = col-slice, lane = row.
__global__ __launch_bounds__(256) void k_out_ffn(
    const float* __restrict__ ctx, const float* __restrict__ x,
    const float* __restrict__ Wo, const float* __restrict__ bo,
    const float* __restrict__ g2, const float* __restrict__ bt2,
    const float* __restrict__ W1, const float* __restrict__ b1,
    const float* __restrict__ W2, const float* __restrict__ b2,
    float* __restrict__ out)
{
    __shared__ float sWo[40][48];
    __shared__ float sW1[40][32];
    __shared__ float sW2[20][48];
    __shared__ float sBo[40], sG2[40], sBt2[40], sB1[20], sB2[40];
    __shared__ float sCtx[64][41];
    __shared__ float sH[64][41];
    __shared__ float sIt[64][21];
    __shared__ float sSum[64][4], sSum2[64][4];

    const int tid = threadIdx.x;
    for (int idx = tid; idx < 1600; idx += 256) {
        int i = idx / 40, j = idx % 40;
        sWo[i][(j / 10) * 12 + (j % 10)] = Wo[idx];
    }
    for (int idx = tid; idx < 800; idx += 256) {
        {
            int i = idx / 20, j = idx % 20;
            sW1[i][(j / 5) * 8 + (j % 5)] = W1[idx];
        }
        {
            int i = idx / 40, j = idx % 40;
            sW2[i][(j / 10) * 12 + (j % 10)] = W2[idx];
        }
    }
    if (tid < 40) { sBo[tid] = bo[tid]; sG2[tid] = g2[tid]; sBt2[tid] = bt2[tid]; sB2[tid] = b2[tid]; }
    if (tid < 20) sB1[tid] = b1[tid];

    const int row0 = blockIdx.x * 64;
    const int b = row0 >> 9, s0 = row0 & 511;

    for (int idx = tid; idx < 640; idx += 256) {
        const int hh = idx / 160, f = idx - hh * 160;
        float4 u = *(const float4*)(ctx + ((size_t)((b * 4 + hh) * 512 + s0)) * 10 + f * 4);
        const int fo = f * 4;
        float e[4] = {u.x, u.y, u.z, u.w};
#pragma unroll
        for (int t = 0; t < 4; t++) {
            const int fe = fo + t;
            const int r = fe / 10, c = fe - r * 10;
            sCtx[r][hh * 10 + c] = e[t];
        }
    }
    const float4* xblk = (const float4*)(x + (size_t)blockIdx.x * 64 * 40);
    for (int idx = tid; idx < 640; idx += 256) {
        float4 w = xblk[idx];
        int fl = idx * 4;
        int r = fl / 40, c = fl - r * 40;
        sH[r][c] = w.x; sH[r][c + 1] = w.y; sH[r][c + 2] = w.z; sH[r][c + 3] = w.w;
    }
    __syncthreads();

    const int lane = tid & 63;
    const int wv = tid >> 6;
    const int j0 = wv * 10;

    float acc[10];
#pragma unroll
    for (int j = 0; j < 10; j++) acc[j] = sBo[j0 + j] + sH[lane][j0 + j];
#pragma unroll 8
    for (int i = 0; i < 40; i++) {
        const float ci = sCtx[lane][i];
        const float4* wrow = (const float4*)&sWo[i][wv * 12];
        float4 w0 = wrow[0], w1 = wrow[1], w2 = wrow[2];
        acc[0] += ci * w0.x; acc[1] += ci * w0.y; acc[2] += ci * w0.z; acc[3] += ci * w0.w;
        acc[4] += ci * w1.x; acc[5] += ci * w1.y; acc[6] += ci * w1.z; acc[7] += ci * w1.w;
        acc[8] += ci * w2.x; acc[9] += ci * w2.y;
    }
    {
        float s1 = 0.f, s2 = 0.f;
#pragma unroll
        for (int j = 0; j < 10; j++) { s1 += acc[j]; s2 += acc[j] * acc[j]; }
        sSum[lane][wv] = s1; sSum2[lane][wv] = s2;
    }
    __syncthreads();
    const float mu = (sSum[lane][0] + sSum[lane][1] + sSum[lane][2] + sSum[lane][3]) * 0.025f;
    const float ex2 = (sSum2[lane][0] + sSum2[lane][1] + sSum2[lane][2] + sSum2[lane][3]) * 0.025f;
    const float rs = rsqrtf(ex2 - mu * mu + EPSF);
#pragma unroll
    for (int j = 0; j < 10; j++)
        sH[lane][j0 + j] = (acc[j] - mu) * rs * sG2[j0 + j] + sBt2[j0 + j];
    __syncthreads();

    const int f0 = wv * 5;
    float it[5];
#pragma unroll
    for (int j = 0; j < 5; j++) it[j] = sB1[f0 + j];
#pragma unroll 8
    for (int i = 0; i < 40; i++) {
        const float hi = sH[lane][i];
        const float4* wrow = (const float4*)&sW1[i][wv * 8];
        float4 w0 = wrow[0], w1 = wrow[1];
        it[0] += hi * w0.x; it[1] += hi * w0.y; it[2] += hi * w0.z; it[3] += hi * w0.w;
        it[4] += hi * w1.x;
    }
#pragma unroll
    for (int j = 0; j < 5; j++) {
        float t = it[j];
        sIt[lane][f0 + j] = 0.5f * t * (1.0f + erff(t * 0.70710678118654752f));
    }
    __syncthreads();

    float o[10];
#pragma unroll
    for (int j = 0; j < 10; j++) o[j] = acc[j] + sB2[j0 + j];
#pragma unroll 4
    for (int i = 0; i < 20; i++) {
        const float ii = sIt[lane][i];
        const float4* wrow = (const float4*)&sW2[i][wv * 12];
        float4 w0 = wrow[0], w1 = wrow[1], w2 = wrow[2];
        o[0] += ii * w0.x; o[1] += ii * w0.y; o[2] += ii * w0.z; o[3] += ii * w0.w;
        o[4] += ii * w1.x; o[5] += ii * w1.y; o[6] += ii * w1.z; o[7] += ii * w1.w;
        o[8] += ii * w2.x; o[9] += ii * w2.y;
    }
#pragma unroll
    for (int j = 0; j < 10; j++) sCtx[lane][j0 + j] = o[j];
    __syncthreads();

    float4* oblk = (float4*)(out + (size_t)blockIdx.x * 64 * 40);
    for (int idx = tid; idx < 640; idx += 256) {
        int fl = idx * 4;
        int r = fl / 40, c = fl - r * 40;
        float4 u;
        u.x = sCtx[r][c]; u.y = sCtx[r][c + 1]; u.z = sCtx[r][c + 2]; u.w = sCtx[r][c + 3];
        oblk[idx] = u;
    }
}

extern "C" void kernel_launch(void* const* d_in, const int* in_sizes, int n_in,
                              void* d_out, int out_size, void* d_ws, size_t ws_size,
                              hipStream_t stream)
{
    const float* x   = (const float*)d_in[0];
    const float* g1  = (const float*)d_in[1];
    const float* be1 = (const float*)d_in[2];
    const float* Wq  = (const float*)d_in[3];
    const float* bq  = (const float*)d_in[4];
    const float* Wk  = (const float*)d_in[5];
    const float* bk  = (const float*)d_in[6];
    const float* Wv  = (const float*)d_in[7];
    const float* bv  = (const float*)d_in[8];
    const float* Wo  = (const float*)d_in[9];
    const float* bo  = (const float*)d_in[10];
    const float* g2  = (const float*)d_in[11];
    const float* bt2 = (const float*)d_in[12];
    const float* W1  = (const float*)d_in[13];
    const float* b1  = (const float*)d_in[14];
    const float* W2  = (const float*)d_in[15];
    const float* b2  = (const float*)d_in[16];

    float* ws = (float*)d_ws;
    const size_t QKV = (size_t)BB * 4 * SS * DPP;  // 1,572,864 floats
    float* q   = ws;
    float* k   = ws + QKV;
    float* v   = ws + 2 * QKV;
    float* ctx = ws + 3 * QKV;  // [B,H,S,10] = 1,310,720 floats

    k_ln_qkv<<<512, 256, 0, stream>>>(x, g1, be1, Wq, bq, Wk, bk, Wv, bv, q, k, v);
    k_attn<<<512, 256, 0, stream>>>(q, k, v, ctx);
    k_out_ffn<<<512, 256, 0, stream>>>(ctx, x, Wo, bo, g2, bt2, W1, b1, W2, b2,
                                       (float*)d_out);
}

// Round 5
// 165.191 us; speedup vs baseline: 1.0163x; 1.0052x over previous
//
#include <hip/hip_runtime.h>
#include <stdint.h>

#define BB 64
#define SS 512
#define DPP 12   // padded head dim (48B rows -> float4 aligned)
#define EPSF 1e-5f

typedef float v2f __attribute__((ext_vector_type(2)));

// ---------------- K1: LN1 + QKV projection (v2) ----------------
// grid 512 x 256. Block = 64 rows; lane = row, wave = head (0..3).
// Weights/biases/gamma/beta are read via wave-uniform loads (scalar pipe,
// L2-resident, no LDS staging, no repack phase, single barrier).
// Each thread computes q/k/v head `part` (3x10 cols) for its row and
// stores directly to the padded [B*H][S][12] layout.
__global__ __launch_bounds__(256) void k_ln_qkv(
    const float* __restrict__ x, const float* __restrict__ g, const float* __restrict__ be,
    const float* __restrict__ Wq, const float* __restrict__ bq,
    const float* __restrict__ Wk, const float* __restrict__ bk,
    const float* __restrict__ Wv, const float* __restrict__ bv,
    float* __restrict__ qo, float* __restrict__ ko, float* __restrict__ vo)
{
    __shared__ float sX[64][41];

    const int tid = threadIdx.x;
    const float4* xblk = (const float4*)(x + (size_t)blockIdx.x * 64 * 40);
    for (int idx = tid; idx < 640; idx += 256) {
        float4 u = xblk[idx];
        int fl = idx * 4;
        int r = fl / 40, c = fl - r * 40;
        sX[r][c] = u.x; sX[r][c + 1] = u.y; sX[r][c + 2] = u.z; sX[r][c + 3] = u.w;
    }
    __syncthreads();

    const int lane = tid & 63;
    const int part = tid >> 6;
    const int hp = __builtin_amdgcn_readfirstlane(part);   // provably uniform head idx

    // LN stats (one LDS pass)
    float s1 = 0.f, s2 = 0.f;
#pragma unroll 8
    for (int i = 0; i < 40; i++) { float v = sX[lane][i]; s1 += v; s2 += v * v; }
    const float mu = s1 * 0.025f;
    const float rs = rsqrtf(s2 * 0.025f - mu * mu + EPSF);

    // normalized row in registers (g/be are uniform loads)
    float hrow[40];
#pragma unroll 4
    for (int i = 0; i < 40; i++)
        hrow[i] = (sX[lane][i] - mu) * rs * g[i] + be[i];

    const float* Wp[3] = {Wq, Wk, Wv};
    const float* Bp[3] = {bq, bk, bv};

    float acc[3][10];
#pragma unroll
    for (int w = 0; w < 3; w++)
#pragma unroll
        for (int c = 0; c < 10; c++) acc[w][c] = Bp[w][hp * 10 + c];

#pragma unroll 2
    for (int i = 0; i < 40; i++) {
        const float hi = hrow[i];
#pragma unroll
        for (int w = 0; w < 3; w++) {
            const float* wp = Wp[w] + i * 40 + hp * 10;   // uniform -> s_load
#pragma unroll
            for (int c = 0; c < 10; c++) acc[w][c] += hi * wp[c];
        }
    }

    const int row0 = blockIdx.x * 64;
    const int b4 = (row0 >> 9) * 4, s0 = row0 & 511;
    float* Op[3] = {qo, ko, vo};
#pragma unroll
    for (int w = 0; w < 3; w++) {
        float* op = Op[w] + ((size_t)((b4 + hp) * 512 + s0 + lane)) * DPP;
        float4 u0 = {acc[w][0], acc[w][1], acc[w][2], acc[w][3]};
        float4 u1 = {acc[w][4], acc[w][5], acc[w][6], acc[w][7]};
        float4 u2 = {acc[w][8], acc[w][9], 0.f, 0.f};
        ((float4*)op)[0] = u0; ((float4*)op)[1] = u1; ((float4*)op)[2] = u2;
    }
}

// ---------------- K2: attention v11 ----------------
// grid 512 = bh x q-half. block 512 = 8 waves = k-eighths (64 keys each).
// QPT=4 (76 VGPR, spill-free per v10). Same per-CU LDS traffic and VALU
// work as v10, but 16 waves/CU (vs 8) so the two ~60%-busy pipes
// (VALU issue ~28us, LDS return ~31us) can overlap: v10/v6 both showed
// dual-pipe ~57% with too few waves to hide the K->dot->exp->V chain.
__global__ __launch_bounds__(512, 2) void k_attn(
    const float* __restrict__ qg, const float* __restrict__ kg,
    const float* __restrict__ vg, float* __restrict__ ctx)
{
    __shared__ float smem[12288];        // 48 KB: sK+sV, aliased as partials
    float4* sK = (float4*)smem;          // [1536]
    float4* sV = sK + 1536;              // [1536]

    const int tid = threadIdx.x;
    const int bh = blockIdx.x >> 1;
    const int qh = blockIdx.x & 1;       // q-half

    const float4* kp = (const float4*)(kg + (size_t)bh * 512 * DPP);
    const float4* vp = (const float4*)(vg + (size_t)bh * 512 * DPP);
    for (int idx = tid; idx < 1536; idx += 512) { sK[idx] = kp[idx]; sV[idx] = vp[idx]; }

    const int lane = tid & 63;
    const int wave = tid >> 6;           // k-eighth
    const int kbase = wave * 64;

    const float cscale = 1.4426950408889634f / 3.1622776601683795f;  // log2e/sqrt(10)
    v2f q[4][5];
#pragma unroll
    for (int jj = 0; jj < 4; jj++) {
        const float2* qp = (const float2*)(qg + ((size_t)bh * 512 + qh * 256 + jj * 64 + lane) * DPP);
#pragma unroll
        for (int c = 0; c < 5; c++) {
            float2 u = qp[c];
            v2f t; t.x = u.x * cscale; t.y = u.y * cscale;
            q[jj][c] = t;
        }
    }
    // Pin q in VGPRs (opaque to remat/sinking).
#pragma unroll
    for (int jj = 0; jj < 4; jj++)
#pragma unroll
        for (int c = 0; c < 5; c++)
            asm volatile("" : "+v"(q[jj][c]));

    __syncthreads();   // staging complete (q loads overlapped with it)

    float l[4];
    v2f a[4][5];
#pragma unroll
    for (int jj = 0; jj < 4; jj++) {
        l[jj] = 0.f;
#pragma unroll
        for (int d = 0; d < 5; d++) a[jj][d] = (v2f)(0.f);
    }

    for (int kt = 0; kt < 64; kt += 2) {
        const int ki = kbase + kt;
        // ---- K phase ----
        const float4 ka0 = sK[ki * 3 + 0], ka1 = sK[ki * 3 + 1], ka2 = sK[ki * 3 + 2];
        const float4 kb0 = sK[ki * 3 + 3], kb1 = sK[ki * 3 + 4], kb2 = sK[ki * 3 + 5];
        v2f ka[5], kb[5];
        ka[0] = v2f{ka0.x, ka0.y}; ka[1] = v2f{ka0.z, ka0.w};
        ka[2] = v2f{ka1.x, ka1.y}; ka[3] = v2f{ka1.z, ka1.w};
        ka[4] = v2f{ka2.x, ka2.y};
        kb[0] = v2f{kb0.x, kb0.y}; kb[1] = v2f{kb0.z, kb0.w};
        kb[2] = v2f{kb1.x, kb1.y}; kb[3] = v2f{kb1.z, kb1.w};
        kb[4] = v2f{kb2.x, kb2.y};
        float pa[4], pb[4];
#pragma unroll
        for (int jj = 0; jj < 4; jj++) {
            v2f da = q[jj][0] * ka[0];
            v2f db = q[jj][0] * kb[0];
#pragma unroll
            for (int c = 1; c < 5; c++) {
                da += q[jj][c] * ka[c];
                db += q[jj][c] * kb[c];
            }
            pa[jj] = __builtin_amdgcn_exp2f(da.x + da.y);
            pb[jj] = __builtin_amdgcn_exp2f(db.x + db.y);
            l[jj] += pa[jj] + pb[jj];
        }
        // ---- V phase ----
        const float4 va0 = sV[ki * 3 + 0], va1 = sV[ki * 3 + 1], va2 = sV[ki * 3 + 2];
        const float4 vb0 = sV[ki * 3 + 3], vb1 = sV[ki * 3 + 4], vb2 = sV[ki * 3 + 5];
        v2f va[5], vb[5];
        va[0] = v2f{va0.x, va0.y}; va[1] = v2f{va0.z, va0.w};
        va[2] = v2f{va1.x, va1.y}; va[3] = v2f{va1.z, va1.w};
        va[4] = v2f{va2.x, va2.y};
        vb[0] = v2f{vb0.x, vb0.y}; vb[1] = v2f{vb0.z, vb0.w};
        vb[2] = v2f{vb1.x, vb1.y}; vb[3] = v2f{vb1.z, vb1.w};
        vb[4] = v2f{vb2.x, vb2.y};
#pragma unroll
        for (int jj = 0; jj < 4; jj++) {
            const v2f pa2 = {pa[jj], pa[jj]};
            const v2f pb2 = {pb[jj], pb[jj]};
#pragma unroll
            for (int d = 0; d < 5; d++)
                a[jj][d] += pa2 * va[d] + pb2 * vb[d];
        }
    }
    __syncthreads();   // all sK/sV reads complete -> safe to alias

    // partial sets: [set 0..3][q-local 0..255][12] = 48 KB aliased over sK/sV
    // phase A: waves 0-3 write sets 0-3
    if (wave < 4) {
#pragma unroll
        for (int jj = 0; jj < 4; jj++) {
            float4* p = (float4*)(smem + ((wave * 256 + jj * 64 + lane) * 12));
            float4 u0, u1, u2;
            u0.x = a[jj][0].x; u0.y = a[jj][0].y; u0.z = a[jj][1].x; u0.w = a[jj][1].y;
            u1.x = a[jj][2].x; u1.y = a[jj][2].y; u1.z = a[jj][3].x; u1.w = a[jj][3].y;
            u2.x = a[jj][4].x; u2.y = a[jj][4].y; u2.z = l[jj];     u2.w = 0.f;
            p[0] = u0; p[1] = u1; p[2] = u2;
        }
    }
    __syncthreads();

    // phase B: waves 4-7 accumulate into set (wave-4)
    if (wave >= 4) {
        const int w = wave - 4;
#pragma unroll
        for (int jj = 0; jj < 4; jj++) {
            float4* p = (float4*)(smem + ((w * 256 + jj * 64 + lane) * 12));
            float4 u0 = p[0], u1 = p[1], u2 = p[2];
            u0.x += a[jj][0].x; u0.y += a[jj][0].y; u0.z += a[jj][1].x; u0.w += a[jj][1].y;
            u1.x += a[jj][2].x; u1.y += a[jj][2].y; u1.z += a[jj][3].x; u1.w += a[jj][3].y;
            u2.x += a[jj][4].x; u2.y += a[jj][4].y; u2.z += l[jj];
            p[0] = u0; p[1] = u1; p[2] = u2;
        }
    }
    __syncthreads();

    // merge: threads 0..255, one query each over 4 sets
    if (tid < 256) {
        float acc[10], lt = 0.f;
#pragma unroll
        for (int d = 0; d < 10; d++) acc[d] = 0.f;
#pragma unroll
        for (int w = 0; w < 4; w++) {
            const float4* p = (const float4*)(smem + ((w * 256 + tid) * 12));
            float4 u0 = p[0], u1 = p[1], u2 = p[2];
            acc[0] += u0.x; acc[1] += u0.y; acc[2] += u0.z; acc[3] += u0.w;
            acc[4] += u1.x; acc[5] += u1.y; acc[6] += u1.z; acc[7] += u1.w;
            acc[8] += u2.x; acc[9] += u2.y; lt += u2.z;
        }
        const float inv = 1.f / lt;
        float* op = ctx + ((size_t)bh * 512 + qh * 256 + tid) * 10;
#pragma unroll
        for (int d = 0; d < 5; d++) {
            float2 u; u.x = acc[d * 2] * inv; u.y = acc[d * 2 + 1] * inv;
            *(float2*)(op + d * 2) = u;
        }
    }
}

// ---------------- K3: Wo + residual + LN2 + FFN + residual ----------------
// grid 512 x 256. Block = 64 rows; wave = col-slice, lane = row.
__global__ __launch_bounds__(256) void k_out_ffn(
    const float* __restrict__ ctx, const float* __restrict__ x,
    const float* __restrict__ Wo, const float* __restrict__ bo,
    const float* __restrict__ g2, const float* __restrict__ bt2,
    const float* __restrict__ W1, const float* __restrict__ b1,
    const float* __restrict__ W2, const float* __restrict__ b2,
    float* __restrict__ out)
{
    __shared__ float sWo[40][48];
    __shared__ float sW1[40][32];
    __shared__ float sW2[20][48];
    __shared__ float sBo[40], sG2[40], sBt2[40], sB1[20], sB2[40];
    __shared__ float sCtx[64][41];
    __shared__ float sH[64][41];
    __shared__ float sIt[64][21];
    __shared__ float sSum[64][4], sSum2[64][4];

    const int tid = threadIdx.x;
    for (int idx = tid; idx < 1600; idx += 256) {
        int i = idx / 40, j = idx % 40;
        sWo[i][(j / 10) * 12 + (j % 10)] = Wo[idx];
    }
    for (int idx = tid; idx < 800; idx += 256) {
        {
            int i = idx / 20, j = idx % 20;
            sW1[i][(j / 5) * 8 + (j % 5)] = W1[idx];
        }
        {
            int i = idx / 40, j = idx % 40;
            sW2[i][(j / 10) * 12 + (j % 10)] = W2[idx];
        }
    }
    if (tid < 40) { sBo[tid] = bo[tid]; sG2[tid] = g2[tid]; sBt2[tid] = bt2[tid]; sB2[tid] = b2[tid]; }
    if (tid < 20) sB1[tid] = b1[tid];

    const int row0 = blockIdx.x * 64;
    const int b = row0 >> 9, s0 = row0 & 511;

    for (int idx = tid; idx < 640; idx += 256) {
        const int hh = idx / 160, f = idx - hh * 160;
        float4 u = *(const float4*)(ctx + ((size_t)((b * 4 + hh) * 512 + s0)) * 10 + f * 4);
        const int fo = f * 4;
        float e[4] = {u.x, u.y, u.z, u.w};
#pragma unroll
        for (int t = 0; t < 4; t++) {
            const int fe = fo + t;
            const int r = fe / 10, c = fe - r * 10;
            sCtx[r][hh * 10 + c] = e[t];
        }
    }
    const float4* xblk = (const float4*)(x + (size_t)blockIdx.x * 64 * 40);
    for (int idx = tid; idx < 640; idx += 256) {
        float4 w = xblk[idx];
        int fl = idx * 4;
        int r = fl / 40, c = fl - r * 40;
        sH[r][c] = w.x; sH[r][c + 1] = w.y; sH[r][c + 2] = w.z; sH[r][c + 3] = w.w;
    }
    __syncthreads();

    const int lane = tid & 63;
    const int wv = tid >> 6;
    const int j0 = wv * 10;

    float acc[10];
#pragma unroll
    for (int j = 0; j < 10; j++) acc[j] = sBo[j0 + j] + sH[lane][j0 + j];
#pragma unroll 8
    for (int i = 0; i < 40; i++) {
        const float ci = sCtx[lane][i];
        const float4* wrow = (const float4*)&sWo[i][wv * 12];
        float4 w0 = wrow[0], w1 = wrow[1], w2 = wrow[2];
        acc[0] += ci * w0.x; acc[1] += ci * w0.y; acc[2] += ci * w0.z; acc[3] += ci * w0.w;
        acc[4] += ci * w1.x; acc[5] += ci * w1.y; acc[6] += ci * w1.z; acc[7] += ci * w1.w;
        acc[8] += ci * w2.x; acc[9] += ci * w2.y;
    }
    {
        float s1 = 0.f, s2 = 0.f;
#pragma unroll
        for (int j = 0; j < 10; j++) { s1 += acc[j]; s2 += acc[j] * acc[j]; }
        sSum[lane][wv] = s1; sSum2[lane][wv] = s2;
    }
    __syncthreads();
    const float mu = (sSum[lane][0] + sSum[lane][1] + sSum[lane][2] + sSum[lane][3]) * 0.025f;
    const float ex2 = (sSum2[lane][0] + sSum2[lane][1] + sSum2[lane][2] + sSum2[lane][3]) * 0.025f;
    const float rs = rsqrtf(ex2 - mu * mu + EPSF);
#pragma unroll
    for (int j = 0; j < 10; j++)
        sH[lane][j0 + j] = (acc[j] - mu) * rs * sG2[j0 + j] + sBt2[j0 + j];
    __syncthreads();

    const int f0 = wv * 5;
    float it[5];
#pragma unroll
    for (int j = 0; j < 5; j++) it[j] = sB1[f0 + j];
#pragma unroll 8
    for (int i = 0; i < 40; i++) {
        const float hi = sH[lane][i];
        const float4* wrow = (const float4*)&sW1[i][wv * 8];
        float4 w0 = wrow[0], w1 = wrow[1];
        it[0] += hi * w0.x; it[1] += hi * w0.y; it[2] += hi * w0.z; it[3] += hi * w0.w;
        it[4] += hi * w1.x;
    }
#pragma unroll
    for (int j = 0; j < 5; j++) {
        float t = it[j];
        sIt[lane][f0 + j] = 0.5f * t * (1.0f + erff(t * 0.70710678118654752f));
    }
    __syncthreads();

    float o[10];
#pragma unroll
    for (int j = 0; j < 10; j++) o[j] = acc[j] + sB2[j0 + j];
#pragma unroll 4
    for (int i = 0; i < 20; i++) {
        const float ii = sIt[lane][i];
        const float4* wrow = (const float4*)&sW2[i][wv * 12];
        float4 w0 = wrow[0], w1 = wrow[1], w2 = wrow[2];
        o[0] += ii * w0.x; o[1] += ii * w0.y; o[2] += ii * w0.z; o[3] += ii * w0.w;
        o[4] += ii * w1.x; o[5] += ii * w1.y; o[6] += ii * w1.z; o[7] += ii * w1.w;
        o[8] += ii * w2.x; o[9] += ii * w2.y;
    }
#pragma unroll
    for (int j = 0; j < 10; j++) sCtx[lane][j0 + j] = o[j];
    __syncthreads();

    float4* oblk = (float4*)(out + (size_t)blockIdx.x * 64 * 40);
    for (int idx = tid; idx < 640; idx += 256) {
        int fl = idx * 4;
        int r = fl / 40, c = fl - r * 40;
        float4 u;
        u.x = sCtx[r][c]; u.y = sCtx[r][c + 1]; u.z = sCtx[r][c + 2]; u.w = sCtx[r][c + 3];
        oblk[idx] = u;
    }
}

extern "C" void kernel_launch(void* const* d_in, const int* in_sizes, int n_in,
                              void* d_out, int out_size, void* d_ws, size_t ws_size,
                              hipStream_t stream)
{
    const float* x   = (const float*)d_in[0];
    const float* g1  = (const float*)d_in[1];
    const float* be1 = (const float*)d_in[2];
    const float* Wq  = (const float*)d_in[3];
    const float* bq  = (const float*)d_in[4];
    const float* Wk  = (const float*)d_in[5];
    const float* bk  = (const float*)d_in[6];
    const float* Wv  = (const float*)d_in[7];
    const float* bv  = (const float*)d_in[8];
    const float* Wo  = (const float*)d_in[9];
    const float* bo  = (const float*)d_in[10];
    const float* g2  = (const float*)d_in[11];
    const float* bt2 = (const float*)d_in[12];
    const float* W1  = (const float*)d_in[13];
    const float* b1  = (const float*)d_in[14];
    const float* W2  = (const float*)d_in[15];
    const float* b2  = (const float*)d_in[16];

    float* ws = (float*)d_ws;
    const size_t QKV = (size_t)BB * 4 * SS * DPP;  // 1,572,864 floats
    float* q   = ws;
    float* k   = ws + QKV;
    float* v   = ws + 2 * QKV;
    float* ctx = ws + 3 * QKV;  // [B,H,S,10] = 1,310,720 floats

    k_ln_qkv<<<512, 256, 0, stream>>>(x, g1, be1, Wq, bq, Wk, bk, Wv, bv, q, k, v);
    k_attn<<<512, 512, 0, stream>>>(q, k, v, ctx);
    k_out_ffn<<<512, 256, 0, stream>>>(ctx, x, Wo, bo, g2, bt2, W1, b1, W2, b2,
                                       (float*)d_out);
}

// Round 6
// 140.131 us; speedup vs baseline: 1.1980x; 1.1788x over previous
//
#include <hip/hip_runtime.h>
#include <stdint.h>

#define BB 64
#define SS 512
#define EPSF 1e-5f

typedef __attribute__((ext_vector_type(8)))  short bh8;    // 8 bf16 = 4 VGPR
typedef __attribute__((ext_vector_type(16))) float fx16;   // 32x32 MFMA acc
typedef __attribute__((ext_vector_type(4)))  int   i32x4;

__device__ __forceinline__ int cvtpk(float a, float b) {
    int r;
    asm("v_cvt_pk_bf16_f32 %0, %1, %2" : "=v"(r) : "v"(a), "v"(b));
    return r;
}

// ---------------- K1: LN1 + QKV projection (bf16 out) ----------------
// grid 512 x 256. Block = 64 rows; lane = row, wave = head (0..3).
// Emits: Q bf16 [bh][512][16] pre-scaled by log2e/sqrt(10) (d 10..15 = 0),
//        K bf16 [bh][512][16],
//        V^T bf16 [bh][16][512] with row 10 = 1.0 (ones-column trick:
//        PV output col 10 = softmax denominator), rows 11..15 = 0.
__global__ __launch_bounds__(256) void k_ln_qkv(
    const float* __restrict__ x, const float* __restrict__ g, const float* __restrict__ be,
    const float* __restrict__ Wq, const float* __restrict__ bq,
    const float* __restrict__ Wk, const float* __restrict__ bk,
    const float* __restrict__ Wv, const float* __restrict__ bv,
    unsigned short* __restrict__ qo, unsigned short* __restrict__ ko,
    unsigned short* __restrict__ vt)
{
    __shared__ float sX[64][41];

    const int tid = threadIdx.x;
    const float4* xblk = (const float4*)(x + (size_t)blockIdx.x * 64 * 40);
    for (int idx = tid; idx < 640; idx += 256) {
        float4 u = xblk[idx];
        int fl = idx * 4;
        int r = fl / 40, c = fl - r * 40;
        sX[r][c] = u.x; sX[r][c + 1] = u.y; sX[r][c + 2] = u.z; sX[r][c + 3] = u.w;
    }
    __syncthreads();

    const int lane = tid & 63;
    const int part = tid >> 6;
    const int hp = __builtin_amdgcn_readfirstlane(part);   // uniform head idx

    float s1 = 0.f, s2 = 0.f;
#pragma unroll 8
    for (int i = 0; i < 40; i++) { float v = sX[lane][i]; s1 += v; s2 += v * v; }
    const float mu = s1 * 0.025f;
    const float rs = rsqrtf(s2 * 0.025f - mu * mu + EPSF);

    float hrow[40];
#pragma unroll 4
    for (int i = 0; i < 40; i++)
        hrow[i] = (sX[lane][i] - mu) * rs * g[i] + be[i];

    const float* Wp[3] = {Wq, Wk, Wv};
    const float* Bp[3] = {bq, bk, bv};

    float acc[3][10];
#pragma unroll
    for (int w = 0; w < 3; w++)
#pragma unroll
        for (int c = 0; c < 10; c++) acc[w][c] = Bp[w][hp * 10 + c];

#pragma unroll 2
    for (int i = 0; i < 40; i++) {
        const float hi = hrow[i];
#pragma unroll
        for (int w = 0; w < 3; w++) {
            const float* wp = Wp[w] + i * 40 + hp * 10;   // uniform -> s_load
#pragma unroll
            for (int c = 0; c < 10; c++) acc[w][c] += hi * wp[c];
        }
    }

    const float cs = 1.4426950408889634f / 3.1622776601683795f;  // log2e/sqrt(10)
#pragma unroll
    for (int c = 0; c < 10; c++) acc[0][c] *= cs;

    const int row0 = blockIdx.x * 64;
    const int b4 = (row0 >> 9) * 4, s0 = row0 & 511;
    const size_t srow = (size_t)(b4 + hp) * 512 + s0 + lane;

    {   // Q
        int p0 = cvtpk(acc[0][0], acc[0][1]);
        int p1 = cvtpk(acc[0][2], acc[0][3]);
        int p2 = cvtpk(acc[0][4], acc[0][5]);
        int p3 = cvtpk(acc[0][6], acc[0][7]);
        int p4 = cvtpk(acc[0][8], acc[0][9]);
        i32x4* dst = (i32x4*)qo + srow * 2;
        dst[0] = (i32x4){p0, p1, p2, p3};
        dst[1] = (i32x4){p4, 0, 0, 0};
    }
    {   // K
        int p0 = cvtpk(acc[1][0], acc[1][1]);
        int p1 = cvtpk(acc[1][2], acc[1][3]);
        int p2 = cvtpk(acc[1][4], acc[1][5]);
        int p3 = cvtpk(acc[1][6], acc[1][7]);
        int p4 = cvtpk(acc[1][8], acc[1][9]);
        i32x4* dst = (i32x4*)ko + srow * 2;
        dst[0] = (i32x4){p0, p1, p2, p3};
        dst[1] = (i32x4){p4, 0, 0, 0};
    }
    {   // V^T scattered by d-row (per-wave: 64 consecutive s -> 128B chunks)
        int p0 = cvtpk(acc[2][0], acc[2][1]);
        int p1 = cvtpk(acc[2][2], acc[2][3]);
        int p2 = cvtpk(acc[2][4], acc[2][5]);
        int p3 = cvtpk(acc[2][6], acc[2][7]);
        int p4 = cvtpk(acc[2][8], acc[2][9]);
        unsigned short* vb = vt + ((size_t)(b4 + hp) * 16) * 512 + (s0 + lane);
        vb[0 * 512] = (unsigned short)(p0 & 0xffff);
        vb[1 * 512] = (unsigned short)((unsigned)p0 >> 16);
        vb[2 * 512] = (unsigned short)(p1 & 0xffff);
        vb[3 * 512] = (unsigned short)((unsigned)p1 >> 16);
        vb[4 * 512] = (unsigned short)(p2 & 0xffff);
        vb[5 * 512] = (unsigned short)((unsigned)p2 >> 16);
        vb[6 * 512] = (unsigned short)(p3 & 0xffff);
        vb[7 * 512] = (unsigned short)((unsigned)p3 >> 16);
        vb[8 * 512] = (unsigned short)(p4 & 0xffff);
        vb[9 * 512] = (unsigned short)((unsigned)p4 >> 16);
        vb[10 * 512] = 0x3F80;   // bf16(1.0) ones-row -> denominator
        vb[11 * 512] = 0; vb[12 * 512] = 0; vb[13 * 512] = 0;
        vb[14 * 512] = 0; vb[15 * 512] = 0;
    }
}

// ---------------- K2: attention v12 (MFMA) ----------------
// grid 512 = bh x q-half. block 256 = 4 waves; wave owns 2 q-tiles of 32.
// QK^T: mfma_32x32x16_bf16(A=K, B=Q) -> S^T tile [32k x 32q], K-dim=16=d.
// Computing S^T makes exp2(S^T) land EXACTLY in PV's A-operand layout up
// to a lane<32/lane>=32 half-exchange = v_permlane32_swap_b32 (T12).
// PV: mfma_32x32x16_bf16(A=P, B=V^T-frag), 16 keys per MFMA; V^T ones-row
// at d=10 accumulates the denominator in acc col 10. One barrier total.
__global__ __launch_bounds__(256) void k_attn(
    const unsigned short* __restrict__ qg, const unsigned short* __restrict__ kg,
    const unsigned short* __restrict__ vt, float* __restrict__ ctx)
{
    // K: 512 rows x 48B (16 bf16 + 16B pad for alignment/banking) = 24576 B
    // V^T: 16 rows x 1040B (512 bf16 + 16B pad) = 16640 B
    __shared__ __align__(16) char smem[24576 + 16640];

    const int tid = threadIdx.x;
    const int bh = blockIdx.x >> 1;
    const int qh = blockIdx.x & 1;
    const int lane = tid & 63;
    const int wave = tid >> 6;

    // Q fragments from global (B-operand: lane l -> Q[q=l&31][d=(l>>5)*8+j])
    bh8 qf0, qf1;
    {
        const char* qp = (const char*)qg + (size_t)bh * 512 * 32;
        const int qbase = qh * 256 + wave * 64;
        qf0 = *(const bh8*)(qp + (size_t)(qbase + (lane & 31)) * 32 + (lane >> 5) * 16);
        qf1 = *(const bh8*)(qp + (size_t)(qbase + 32 + (lane & 31)) * 32 + (lane >> 5) * 16);
    }
    // stage K (1024 x 16B chunks -> 48B rows) and V^T (-> 1040B rows)
    {
        const i32x4* gk = (const i32x4*)((const char*)kg + (size_t)bh * 512 * 32);
        for (int c = tid; c < 1024; c += 256) {
            i32x4 u = gk[c];
            *(i32x4*)(smem + (c >> 1) * 48 + (c & 1) * 16) = u;
        }
        const i32x4* gv = (const i32x4*)((const char*)vt + (size_t)bh * 16 * 1024);
        for (int c = tid; c < 1024; c += 256) {
            i32x4 u = gv[c];
            *(i32x4*)(smem + 24576 + (c >> 6) * 1040 + (c & 63) * 16) = u;
        }
    }
    __syncthreads();

    const char* sK = smem;
    const char* sV = smem + 24576;
    const int krow = lane & 31, khalf = lane >> 5;
    const int vrow = lane & 15;
    const bool vzero = (lane & 16) != 0;   // B cols d>=16 must be zero

    fx16 acc0 = (fx16)(0.0f), acc1 = (fx16)(0.0f);

    for (int kt = 0; kt < 16; ++kt) {      // 32 keys per iteration
        bh8 kf  = *(const bh8*)(sK + (kt * 32 + krow) * 48 + khalf * 16);
        bh8 vf0 = *(const bh8*)(sV + vrow * 1040 + kt * 64 + khalf * 16);
        bh8 vf1 = *(const bh8*)(sV + vrow * 1040 + kt * 64 + 32 + khalf * 16);
        if (vzero) { vf0 = (bh8)(short)0; vf1 = (bh8)(short)0; }
#pragma unroll
        for (int qt = 0; qt < 2; ++qt) {
            fx16 s = __builtin_amdgcn_mfma_f32_32x32x16_bf16(
                kf, qt ? qf1 : qf0, (fx16)(0.0f), 0, 0, 0);
            float e[16];
#pragma unroll
            for (int r = 0; r < 16; ++r) e[r] = __builtin_amdgcn_exp2f(s[r]);
            int c0 = cvtpk(e[0], e[1]),   c1 = cvtpk(e[2], e[3]);
            int c2 = cvtpk(e[4], e[5]),   c3 = cvtpk(e[6], e[7]);
            int c4 = cvtpk(e[8], e[9]),   c5 = cvtpk(e[10], e[11]);
            int c6 = cvtpk(e[12], e[13]), c7 = cvtpk(e[14], e[15]);
            // redistribute P across the 32-lane halves into A-operand order
            asm("v_permlane32_swap_b32 %0, %1" : "+v"(c0), "+v"(c2));
            asm("v_permlane32_swap_b32 %0, %1" : "+v"(c1), "+v"(c3));
            asm("v_permlane32_swap_b32 %0, %1" : "+v"(c4), "+v"(c6));
            asm("v_permlane32_swap_b32 %0, %1" : "+v"(c5), "+v"(c7));
            union { i32x4 i; bh8 h; } lo, hi;
            lo.i = (i32x4){c0, c1, c2, c3};   // P[q][k 0..15 of this kt]
            hi.i = (i32x4){c4, c5, c6, c7};   // P[q][k 16..31]
            if (qt == 0) {
                acc0 = __builtin_amdgcn_mfma_f32_32x32x16_bf16(lo.h, vf0, acc0, 0, 0, 0);
                acc0 = __builtin_amdgcn_mfma_f32_32x32x16_bf16(hi.h, vf1, acc0, 0, 0, 0);
            } else {
                acc1 = __builtin_amdgcn_mfma_f32_32x32x16_bf16(lo.h, vf0, acc1, 0, 0, 0);
                acc1 = __builtin_amdgcn_mfma_f32_32x32x16_bf16(hi.h, vf1, acc1, 0, 0, 0);
            }
        }
    }

    // epilogue: col 10 holds denominator; broadcast within 32-group, divide, store
    const int d = lane & 31;
    const int qb = qh * 256 + wave * 64;
#pragma unroll
    for (int qt = 0; qt < 2; ++qt) {
        fx16 A = qt ? acc1 : acc0;
#pragma unroll
        for (int r = 0; r < 16; ++r) {
            float v = A[r];
            float ls = __shfl(v, (lane & 32) | 10, 64);
            float o = v / ls;
            if (d < 10) {
                int q = qb + qt * 32 + (r & 3) + 8 * (r >> 2) + 4 * (lane >> 5);
                ctx[((size_t)bh * 512 + q) * 10 + d] = o;
            }
        }
    }
}

// ---------------- K3: Wo + residual + LN2 + FFN + residual ----------------
// grid 512 x 256. Block = 64 rows; wave = col-slice, lane = row. (unchanged)
__global__ __launch_bounds__(256) void k_out_ffn(
    const float* __restrict__ ctx, const float* __restrict__ x,
    const float* __restrict__ Wo, const float* __restrict__ bo,
    const float* __restrict__ g2, const float* __restrict__ bt2,
    const float* __restrict__ W1, const float* __restrict__ b1,
    const float* __restrict__ W2, const float* __restrict__ b2,
    float* __restrict__ out)
{
    __shared__ float sWo[40][48];
    __shared__ float sW1[40][32];
    __shared__ float sW2[20][48];
    __shared__ float sBo[40], sG2[40], sBt2[40], sB1[20], sB2[40];
    __shared__ float sCtx[64][41];
    __shared__ float sH[64][41];
    __shared__ float sIt[64][21];
    __shared__ float sSum[64][4], sSum2[64][4];

    const int tid = threadIdx.x;
    for (int idx = tid; idx < 1600; idx += 256) {
        int i = idx / 40, j = idx % 40;
        sWo[i][(j / 10) * 12 + (j % 10)] = Wo[idx];
    }
    for (int idx = tid; idx < 800; idx += 256) {
        {
            int i = idx / 20, j = idx % 20;
            sW1[i][(j / 5) * 8 + (j % 5)] = W1[idx];
        }
        {
            int i = idx / 40, j = idx % 40;
            sW2[i][(j / 10) * 12 + (j % 10)] = W2[idx];
        }
    }
    if (tid < 40) { sBo[tid] = bo[tid]; sG2[tid] = g2[tid]; sBt2[tid] = bt2[tid]; sB2[tid] = b2[tid]; }
    if (tid < 20) sB1[tid] = b1[tid];

    const int row0 = blockIdx.x * 64;
    const int b = row0 >> 9, s0 = row0 & 511;

    for (int idx = tid; idx < 640; idx += 256) {
        const int hh = idx / 160, f = idx - hh * 160;
        float4 u = *(const float4*)(ctx + ((size_t)((b * 4 + hh) * 512 + s0)) * 10 + f * 4);
        const int fo = f * 4;
        float e[4] = {u.x, u.y, u.z, u.w};
#pragma unroll
        for (int t = 0; t < 4; t++) {
            const int fe = fo + t;
            const int r = fe / 10, c = fe - r * 10;
            sCtx[r][hh * 10 + c] = e[t];
        }
    }
    const float4* xblk = (const float4*)(x + (size_t)blockIdx.x * 64 * 40);
    for (int idx = tid; idx < 640; idx += 256) {
        float4 w = xblk[idx];
        int fl = idx * 4;
        int r = fl / 40, c = fl - r * 40;
        sH[r][c] = w.x; sH[r][c + 1] = w.y; sH[r][c + 2] = w.z; sH[r][c + 3] = w.w;
    }
    __syncthreads();

    const int lane = tid & 63;
    const int wv = tid >> 6;
    const int j0 = wv * 10;

    float acc[10];
#pragma unroll
    for (int j = 0; j < 10; j++) acc[j] = sBo[j0 + j] + sH[lane][j0 + j];
#pragma unroll 8
    for (int i = 0; i < 40; i++) {
        const float ci = sCtx[lane][i];
        const float4* wrow = (const float4*)&sWo[i][wv * 12];
        float4 w0 = wrow[0], w1 = wrow[1], w2 = wrow[2];
        acc[0] += ci * w0.x; acc[1] += ci * w0.y; acc[2] += ci * w0.z; acc[3] += ci * w0.w;
        acc[4] += ci * w1.x; acc[5] += ci * w1.y; acc[6] += ci * w1.z; acc[7] += ci * w1.w;
        acc[8] += ci * w2.x; acc[9] += ci * w2.y;
    }
    {
        float s1 = 0.f, s2 = 0.f;
#pragma unroll
        for (int j = 0; j < 10; j++) { s1 += acc[j]; s2 += acc[j] * acc[j]; }
        sSum[lane][wv] = s1; sSum2[lane][wv] = s2;
    }
    __syncthreads();
    const float mu = (sSum[lane][0] + sSum[lane][1] + sSum[lane][2] + sSum[lane][3]) * 0.025f;
    const float ex2 = (sSum2[lane][0] + sSum2[lane][1] + sSum2[lane][2] + sSum2[lane][3]) * 0.025f;
    const float rs = rsqrtf(ex2 - mu * mu + EPSF);
#pragma unroll
    for (int j = 0; j < 10; j++)
        sH[lane][j0 + j] = (acc[j] - mu) * rs * sG2[j0 + j] + sBt2[j0 + j];
    __syncthreads();

    const int f0 = wv * 5;
    float it[5];
#pragma unroll
    for (int j = 0; j < 5; j++) it[j] = sB1[f0 + j];
#pragma unroll 8
    for (int i = 0; i < 40; i++) {
        const float hi = sH[lane][i];
        const float4* wrow = (const float4*)&sW1[i][wv * 8];
        float4 w0 = wrow[0], w1 = wrow[1];
        it[0] += hi * w0.x; it[1] += hi * w0.y; it[2] += hi * w0.z; it[3] += hi * w0.w;
        it[4] += hi * w1.x;
    }
#pragma unroll
    for (int j = 0; j < 5; j++) {
        float t = it[j];
        sIt[lane][f0 + j] = 0.5f * t * (1.0f + erff(t * 0.70710678118654752f));
    }
    __syncthreads();

    float o[10];
#pragma unroll
    for (int j = 0; j < 10; j++) o[j] = acc[j] + sB2[j0 + j];
#pragma unroll 4
    for (int i = 0; i < 20; i++) {
        const float ii = sIt[lane][i];
        const float4* wrow = (const float4*)&sW2[i][wv * 12];
        float4 w0 = wrow[0], w1 = wrow[1], w2 = wrow[2];
        o[0] += ii * w0.x; o[1] += ii * w0.y; o[2] += ii * w0.z; o[3] += ii * w0.w;
        o[4] += ii * w1.x; o[5] += ii * w1.y; o[6] += ii * w1.z; o[7] += ii * w1.w;
        o[8] += ii * w2.x; o[9] += ii * w2.y;
    }
#pragma unroll
    for (int j = 0; j < 10; j++) sCtx[lane][j0 + j] = o[j];
    __syncthreads();

    float4* oblk = (float4*)(out + (size_t)blockIdx.x * 64 * 40);
    for (int idx = tid; idx < 640; idx += 256) {
        int fl = idx * 4;
        int r = fl / 40, c = fl - r * 40;
        float4 u;
        u.x = sCtx[r][c]; u.y = sCtx[r][c + 1]; u.z = sCtx[r][c + 2]; u.w = sCtx[r][c + 3];
        oblk[idx] = u;
    }
}

extern "C" void kernel_launch(void* const* d_in, const int* in_sizes, int n_in,
                              void* d_out, int out_size, void* d_ws, size_t ws_size,
                              hipStream_t stream)
{
    const float* x   = (const float*)d_in[0];
    const float* g1  = (const float*)d_in[1];
    const float* be1 = (const float*)d_in[2];
    const float* Wq  = (const float*)d_in[3];
    const float* bq  = (const float*)d_in[4];
    const float* Wk  = (const float*)d_in[5];
    const float* bk  = (const float*)d_in[6];
    const float* Wv  = (const float*)d_in[7];
    const float* bv  = (const float*)d_in[8];
    const float* Wo  = (const float*)d_in[9];
    const float* bo  = (const float*)d_in[10];
    const float* g2  = (const float*)d_in[11];
    const float* bt2 = (const float*)d_in[12];
    const float* W1  = (const float*)d_in[13];
    const float* b1  = (const float*)d_in[14];
    const float* W2  = (const float*)d_in[15];
    const float* b2  = (const float*)d_in[16];

    unsigned short* wsu = (unsigned short*)d_ws;
    const size_t T = (size_t)256 * 512 * 16;   // 2,097,152 ushorts = 4 MB per tensor
    unsigned short* q  = wsu;
    unsigned short* k  = wsu + T;
    unsigned short* vt = wsu + 2 * T;
    float* ctx = (float*)(wsu + 3 * T);        // [B*H][S][10] f32, 5.24 MB

    k_ln_qkv<<<512, 256, 0, stream>>>(x, g1, be1, Wq, bq, Wk, bk, Wv, bv, q, k, vt);
    k_attn<<<512, 256, 0, stream>>>(q, k, vt, ctx);
    k_out_ffn<<<512, 256, 0, stream>>>(ctx, x, Wo, bo, g2, bt2, W1, b1, W2, b2,
                                       (float*)d_out);
}